// Round 1
// baseline (1845.952 us; speedup 1.0000x reference)
//
#include <hip/hip_runtime.h>
#include <hip/hip_bf16.h>
#include <stdint.h>

// Problem constants
#define Bb 64
#define Qq 64
#define Tt 448
#define Dd 512
#define FDd 1024
#define Hh 8
#define NL 2
#define FFf 2048
#define Ss 512
#define DHh 64

typedef unsigned short u16;
typedef __bf16 bf16x8 __attribute__((ext_vector_type(8)));
typedef float f32x4 __attribute__((ext_vector_type(4)));
typedef float fv4 __attribute__((ext_vector_type(4)));
typedef u16 u16x4 __attribute__((ext_vector_type(4)));

__device__ __forceinline__ float bf2f(u16 u) { return __uint_as_float(((uint32_t)u) << 16); }
__device__ __forceinline__ u16 f2bfu(float f) {
    uint32_t x = __float_as_uint(f);
    uint32_t r = x + 0x7FFFu + ((x >> 16) & 1u);
    return (u16)(r >> 16);
}
// Dual-mode load: input tensors may be bf16 (flag=1) or fp32 (flag=0)
__device__ __forceinline__ float ldx(const void* p, long i, int isbf) {
    return isbf ? bf2f(((const u16*)p)[i]) : ((const float*)p)[i];
}
__device__ __forceinline__ float geluf(float v) {
    return 0.5f * v * (1.0f + erff(v * 0.7071067811865475f));
}
// async global->LDS, 16B per lane; lds ptr must be wave-uniform base (HW adds lane*16)
__device__ __forceinline__ void gload16(const void* g, void* l) {
    __builtin_amdgcn_global_load_lds((const __attribute__((address_space(1))) void*)g,
                                     (__attribute__((address_space(3))) void*)l, 16, 0, 0);
}
#define MFMA16(a, b, c) __builtin_amdgcn_mfma_f32_16x16x32_bf16(a, b, c, 0, 0, 0)

// ---------------- dtype probe ----------------
// pos_emb[0,:2] = (sin0, cos0) = (0,1). bf16-packed word = 0x3F800000; fp32 word = 0.
__global__ void probe_kernel(const void* pos_emb, int* flag) {
    if (threadIdx.x == 0) {
        uint32_t w = *(const uint32_t*)pos_emb;
        *flag = (w == 0x3F800000u) ? 1 : 0;
    }
}

// ---------------- convert (video -> canonical bf16) ----------------
__global__ void convert_kernel(const void* __restrict__ src, u16* __restrict__ dst, long n,
                               const int* __restrict__ flag) {
    const int isbf = *flag;
    long i = (long)blockIdx.x * blockDim.x + threadIdx.x;
    long stride = (long)gridDim.x * blockDim.x;
    for (; i < n; i += stride) {
        dst[i] = isbf ? ((const u16*)src)[i] : f2bfu(((const float*)src)[i]);
    }
}

// ---------------- dual-mode weight transpose: W[R,C] -> Wt[C,R] (bf16 out) -------------
__global__ void transpose_kernel(const void* __restrict__ src, u16* __restrict__ dst,
                                 int R, int C, long elem_off, const int* __restrict__ flag) {
    __shared__ u16 tile[32][33];
    const int isbf = *flag;
    const int c0 = blockIdx.x * 32, r0 = blockIdx.y * 32;
    const int tx = threadIdx.x, ty = threadIdx.y;
#pragma unroll
    for (int i = 0; i < 32; i += 8) {
        long idx = elem_off + (long)(r0 + ty + i) * C + (c0 + tx);
        tile[ty + i][tx] = isbf ? ((const u16*)src)[idx] : f2bfu(((const float*)src)[idx]);
    }
    __syncthreads();
#pragma unroll
    for (int i = 0; i < 32; i += 8) {
        dst[(long)(c0 + ty + i) * R + (r0 + tx)] = tile[tx][ty + i];
    }
}

// ---------------- MFMA GEMM: C[M,N] = A[M,K] @ Bt[N,K]^T + bias, epilogue by MODE -------
// MODE 0: out fp32 [M,N]
// MODE 1: out bf16 [M,N], gelu
// MODE 2: out bf16 scatter [B,H,S,DH], scaled by 1/8 (q)
// MODE 3: out bf16 scatter [B,H,S,DH] (k)
// MODE 4: out bf16 scatter [B,H,DH,S] (v transposed)
template <int MODE>
__global__ __launch_bounds__(256) void gemm_kernel(const u16* __restrict__ A,
                                                   const u16* __restrict__ Bt,
                                                   const void* __restrict__ bias, long bias_off,
                                                   void* __restrict__ out, int M, int N, int K,
                                                   const int* __restrict__ flag) {
    __shared__ __align__(16) u16 sA[128 * 32];
    __shared__ __align__(16) u16 sB[128 * 32];
    const int tid = threadIdx.x;
    const int lane = tid & 63, wave = tid >> 6;
    const int wm = wave >> 1, wn = wave & 1;
    const int col16 = lane & 15, quad = lane >> 4;
    const long m0 = (long)blockIdx.y * 128;
    const long n0 = (long)blockIdx.x * 128;

    f32x4 acc[4][4];
#pragma unroll
    for (int i = 0; i < 4; i++)
#pragma unroll
        for (int j = 0; j < 4; j++) acc[i][j] = (f32x4){0.f, 0.f, 0.f, 0.f};

    for (int k0 = 0; k0 < K; k0 += 32) {
        __syncthreads();
#pragma unroll
        for (int i = 0; i < 2; i++) {
            int slot = tid + i * 256;
            int r = slot >> 2, kq = slot & 3;
            int lbase = (wave * 64 + i * 256) * 8;  // wave-uniform LDS base (elems)
            gload16(&A[(m0 + r) * K + k0 + kq * 8], &sA[lbase]);
            gload16(&Bt[(n0 + r) * K + k0 + kq * 8], &sB[lbase]);
        }
        __syncthreads();
        bf16x8 af[4], bfv[4];
#pragma unroll
        for (int mi = 0; mi < 4; mi++)
            af[mi] = *(const bf16x8*)&sA[(wm * 64 + mi * 16 + col16) * 32 + quad * 8];
#pragma unroll
        for (int ni = 0; ni < 4; ni++)
            bfv[ni] = *(const bf16x8*)&sB[(wn * 64 + ni * 16 + col16) * 32 + quad * 8];
#pragma unroll
        for (int mi = 0; mi < 4; mi++)
#pragma unroll
            for (int ni = 0; ni < 4; ni++)
                acc[mi][ni] = MFMA16(af[mi], bfv[ni], acc[mi][ni]);
    }

    const int isbf = *flag;
    float bb[4];
#pragma unroll
    for (int ni = 0; ni < 4; ni++)
        bb[ni] = ldx(bias, bias_off + n0 + wn * 64 + ni * 16 + col16, isbf);

#pragma unroll
    for (int mi = 0; mi < 4; mi++) {
#pragma unroll
        for (int ni = 0; ni < 4; ni++) {
            long col = n0 + wn * 64 + ni * 16 + col16;
#pragma unroll
            for (int r = 0; r < 4; r++) {
                long row = m0 + wm * 64 + mi * 16 + quad * 4 + r;
                float v = acc[mi][ni][r] + bb[ni];
                if (MODE == 0) {
                    ((float*)out)[row * N + col] = v;
                } else if (MODE == 1) {
                    ((u16*)out)[row * N + col] = f2bfu(geluf(v));
                } else if (MODE == 2 || MODE == 3) {
                    if (MODE == 2) v *= 0.125f;  // 1/sqrt(DH)
                    long b = row >> 9, s = row & 511;
                    long h = col >> 6, dh = col & 63;
                    ((u16*)out)[(((b * 8 + h) * 512) + s) * 64 + dh] = f2bfu(v);
                } else {  // MODE 4: v^T  [B,H,DH,S]
                    long b = row >> 9, s = row & 511;
                    long h = col >> 6, dh = col & 63;
                    ((u16*)out)[(((b * 8 + h) * 64) + dh) * 512 + s] = f2bfu(v);
                }
            }
        }
    }
}

// ---------------- wave-level LN helpers (one wave per row of 512) ----------------
__device__ __forceinline__ float wredsum(float v) {
#pragma unroll
    for (int off = 1; off < 64; off <<= 1) v += __shfl_xor(v, off);
    return v;
}
__device__ __forceinline__ void ln8(float v[8]) {
    float s = 0.f;
#pragma unroll
    for (int j = 0; j < 8; j++) s += v[j];
    s = wredsum(s);
    float m = s * (1.0f / 512.0f);
    float q = 0.f;
#pragma unroll
    for (int j = 0; j < 8; j++) {
        v[j] -= m;
        q += v[j] * v[j];
    }
    q = wredsum(q);
    float inv = rsqrtf(q * (1.0f / 512.0f) + 1e-12f);
#pragma unroll
    for (int j = 0; j < 8; j++) v[j] *= inv;
}

// ---------------- embed: concat(question, LN(videoproj)) + pos + mod, LN ---------------
__global__ __launch_bounds__(256) void embed_kernel(
    const void* __restrict__ question, const void* __restrict__ pos, const void* __restrict__ mod,
    const float* __restrict__ tmp, const void* __restrict__ nvg, const void* __restrict__ nvb,
    const void* __restrict__ eg, const void* __restrict__ eb, u16* __restrict__ x,
    const int* __restrict__ flag) {
    const int isbf = *flag;
    const int wave = threadIdx.x >> 6, lane = threadIdx.x & 63;
    const long row = (long)blockIdx.x * 4 + wave;
    const int b = (int)(row >> 9), s = (int)(row & 511);
    const int d0 = lane * 4, d1 = 256 + lane * 4;
    float v[8];
    if (s < Qq) {
        long base = ((long)b * Qq + s) * Dd;
#pragma unroll
        for (int j = 0; j < 4; j++) {
            v[j] = ldx(question, base + d0 + j, isbf);
            v[4 + j] = ldx(question, base + d1 + j, isbf);
        }
    } else {
        const float* tr = tmp + ((long)b * Tt + (s - Qq)) * Dd;
        fv4 f0 = *(const fv4*)(tr + d0);
        fv4 f1 = *(const fv4*)(tr + d1);
#pragma unroll
        for (int j = 0; j < 4; j++) {
            v[j] = f0[j];
            v[4 + j] = f1[j];
        }
        ln8(v);
#pragma unroll
        for (int j = 0; j < 4; j++) {
            v[j] = v[j] * ldx(nvg, d0 + j, isbf) + ldx(nvb, d0 + j, isbf);
            v[4 + j] = v[4 + j] * ldx(nvg, d1 + j, isbf) + ldx(nvb, d1 + j, isbf);
        }
    }
    const int mid = (s < Qq) ? 0 : 1;
#pragma unroll
    for (int j = 0; j < 4; j++) {
        v[j] += ldx(pos, (long)s * Dd + d0 + j, isbf) + ldx(mod, (long)mid * Dd + d0 + j, isbf);
        v[4 + j] += ldx(pos, (long)s * Dd + d1 + j, isbf) + ldx(mod, (long)mid * Dd + d1 + j, isbf);
    }
    ln8(v);
#pragma unroll
    for (int j = 0; j < 4; j++) {
        x[row * Dd + d0 + j] = f2bfu(v[j] * ldx(eg, d0 + j, isbf) + ldx(eb, d0 + j, isbf));
        x[row * Dd + d1 + j] = f2bfu(v[4 + j] * ldx(eg, d1 + j, isbf) + ldx(eb, d1 + j, isbf));
    }
}

// ---------------- add residual + LN ----------------
__global__ __launch_bounds__(256) void add_ln_kernel(const float* __restrict__ tmp,
                                                     const u16* __restrict__ xin,
                                                     const void* __restrict__ g,
                                                     const void* __restrict__ bta, long goff,
                                                     void* __restrict__ dst, int dst_is_final,
                                                     const int* __restrict__ flag) {
    const int isbf = *flag;
    const int wave = threadIdx.x >> 6, lane = threadIdx.x & 63;
    const long row = (long)blockIdx.x * 4 + wave;
    const int d0 = lane * 4, d1 = 256 + lane * 4;
    const float* tr = tmp + row * Dd;
    fv4 f0 = *(const fv4*)(tr + d0);
    fv4 f1 = *(const fv4*)(tr + d1);
    u16x4 x0 = *(const u16x4*)(xin + row * Dd + d0);
    u16x4 x1 = *(const u16x4*)(xin + row * Dd + d1);
    float v[8];
#pragma unroll
    for (int j = 0; j < 4; j++) {
        v[j] = f0[j] + bf2f(x0[j]);
        v[4 + j] = f1[j] + bf2f(x1[j]);
    }
    ln8(v);
#pragma unroll
    for (int j = 0; j < 8; j++) {
        int d = (j < 4) ? d0 + j : d1 + j - 4;
        v[j] = v[j] * ldx(g, goff + d, isbf) + ldx(bta, goff + d, isbf);
    }
    if (dst_is_final && !isbf) {
#pragma unroll
        for (int j = 0; j < 4; j++) {
            ((float*)dst)[row * Dd + d0 + j] = v[j];
            ((float*)dst)[row * Dd + d1 + j] = v[4 + j];
        }
    } else {
#pragma unroll
        for (int j = 0; j < 4; j++) {
            ((u16*)dst)[row * Dd + d0 + j] = f2bfu(v[j]);
            ((u16*)dst)[row * Dd + d1 + j] = f2bfu(v[4 + j]);
        }
    }
}

// ---------------- flash attention: one wave per 16 q-rows ----------------
// q,k: [B,H,S,DH] bf16 (q pre-scaled); vT: [B,H,DH,S] bf16; ctx out: [B,S,D] bf16
__global__ __launch_bounds__(256) void flash_kernel(const u16* __restrict__ q,
                                                    const u16* __restrict__ k,
                                                    const u16* __restrict__ vT,
                                                    const int* __restrict__ mask,
                                                    u16* __restrict__ ctx) {
    __shared__ __align__(16) u16 pbuf[4][16 * 64];
    const int lane = threadIdx.x & 63, wave = threadIdx.x >> 6;
    const int col16 = lane & 15, quad = lane >> 4;
    const int b = blockIdx.z, h = blockIdx.y;
    const int q0 = blockIdx.x * 64 + wave * 16;
    const long bh = (long)b * Hh + h;
    const u16* qp = q + bh * Ss * DHh;
    const u16* kp = k + bh * Ss * DHh;
    const u16* vp = vT + bh * DHh * Ss;

    bf16x8 aq0 = *(const bf16x8*)&qp[(q0 + col16) * 64 + quad * 8];
    bf16x8 aq1 = *(const bf16x8*)&qp[(q0 + col16) * 64 + 32 + quad * 8];

    float mr[4], lr[4];
    f32x4 acc[4];
#pragma unroll
    for (int r = 0; r < 4; r++) {
        mr[r] = -__builtin_inff();
        lr[r] = 0.f;
    }
#pragma unroll
    for (int dt = 0; dt < 4; dt++) acc[dt] = (f32x4){0.f, 0.f, 0.f, 0.f};

    for (int c0 = 0; c0 < Ss; c0 += 64) {
        f32x4 sc[4];
#pragma unroll
        for (int nt = 0; nt < 4; nt++) {
            int sk = c0 + nt * 16 + col16;
            bf16x8 bk0 = *(const bf16x8*)&kp[sk * 64 + quad * 8];
            bf16x8 bk1 = *(const bf16x8*)&kp[sk * 64 + 32 + quad * 8];
            f32x4 z = (f32x4){0.f, 0.f, 0.f, 0.f};
            z = MFMA16(aq0, bk0, z);
            z = MFMA16(aq1, bk1, z);
            if (mask[b * Ss + sk] == 0) {
#pragma unroll
                for (int r = 0; r < 4; r++) z[r] = -__builtin_inff();
            }
            sc[nt] = z;
        }
        float alpha[4];
#pragma unroll
        for (int r = 0; r < 4; r++) {
            float cm = fmaxf(fmaxf(sc[0][r], sc[1][r]), fmaxf(sc[2][r], sc[3][r]));
#pragma unroll
            for (int off = 1; off < 16; off <<= 1) cm = fmaxf(cm, __shfl_xor(cm, off));
            float mn = fmaxf(mr[r], cm);
            alpha[r] = (mr[r] >= mn) ? 1.0f : __expf(mr[r] - mn);
            float rsum = 0.f;
#pragma unroll
            for (int nt = 0; nt < 4; nt++) {
                float p = sc[nt][r];
                p = (p == -__builtin_inff()) ? 0.f : __expf(p - mn);
                rsum += p;
                pbuf[wave][(quad * 4 + r) * 64 + nt * 16 + col16] = f2bfu(p);
            }
#pragma unroll
            for (int off = 1; off < 16; off <<= 1) rsum += __shfl_xor(rsum, off);
            lr[r] = lr[r] * alpha[r] + rsum;
            mr[r] = mn;
        }
#pragma unroll
        for (int dt = 0; dt < 4; dt++) {
#pragma unroll
            for (int r = 0; r < 4; r++) acc[dt][r] *= alpha[r];
        }
        // P (C-layout) -> A-operand layout via per-wave LDS; same-wave DS ops are in-order.
#pragma unroll
        for (int hf = 0; hf < 2; hf++) {
            bf16x8 ap = *(const bf16x8*)&pbuf[wave][col16 * 64 + hf * 32 + quad * 8];
#pragma unroll
            for (int dt = 0; dt < 4; dt++) {
                bf16x8 bv = *(const bf16x8*)&vp[(dt * 16 + col16) * Ss + c0 + hf * 32 + quad * 8];
                acc[dt] = MFMA16(ap, bv, acc[dt]);
            }
        }
    }
#pragma unroll
    for (int dt = 0; dt < 4; dt++) {
#pragma unroll
        for (int r = 0; r < 4; r++) {
            float v = acc[dt][r] / lr[r];
            int sq = q0 + quad * 4 + r;
            int d = h * 64 + dt * 16 + col16;
            ctx[((long)b * Ss + sq) * Dd + d] = f2bfu(v);
        }
    }
}

// ---------------- host ----------------
extern "C" void kernel_launch(void* const* d_in, const int* in_sizes, int n_in, void* d_out,
                              int out_size, void* d_ws, size_t ws_size, hipStream_t stream) {
    const void* video = d_in[0];
    const void* question = d_in[1];
    const int* mask = (const int*)d_in[2];
    const void* pos_emb = d_in[3];
    const void* mod_emb = d_in[4];
    const void* Wv = d_in[5];
    const void* bv = d_in[6];
    const void* nv_g = d_in[7];
    const void* nv_b = d_in[8];
    const void* emb_g = d_in[9];
    const void* emb_b = d_in[10];
    const void* Wq = d_in[11];
    const void* bq = d_in[12];
    const void* Wk = d_in[13];
    const void* bk = d_in[14];
    const void* Wva = d_in[15];
    const void* bva = d_in[16];
    const void* Wo = d_in[17];
    const void* bo = d_in[18];
    const void* ln1_g = d_in[19];
    const void* ln1_b = d_in[20];
    const void* W1 = d_in[21];
    const void* b1 = d_in[22];
    const void* W2 = d_in[23];
    const void* b2 = d_in[24];
    const void* ln2_g = d_in[25];
    const void* ln2_b = d_in[26];

    char* wsb = (char*)d_ws;
    size_t off = 0;
    auto alloc = [&](size_t bytes) -> void* {
        void* p = (void*)(wsb + off);
        off += (bytes + 4095) & ~((size_t)4095);
        return p;
    };
    int* flag = (int*)alloc(16);
    u16* WvT = (u16*)alloc((size_t)Dd * FDd * 2);
    u16 *WqT[NL], *WkT[NL], *WvaT[NL], *WoT[NL], *W1T[NL], *W2T[NL];
    for (int i = 0; i < NL; i++) {
        WqT[i] = (u16*)alloc((size_t)Dd * Dd * 2);
        WkT[i] = (u16*)alloc((size_t)Dd * Dd * 2);
        WvaT[i] = (u16*)alloc((size_t)Dd * Dd * 2);
        WoT[i] = (u16*)alloc((size_t)Dd * Dd * 2);
        W1T[i] = (u16*)alloc((size_t)FFf * Dd * 2);
        W2T[i] = (u16*)alloc((size_t)Dd * FFf * 2);
    }
    u16* x = (u16*)alloc((size_t)Bb * Ss * Dd * 2);      // 32 MB residual stream (bf16)
    float* tmp = (float*)alloc((size_t)Bb * Ss * Dd * 4);  // 64 MB fp32 GEMM out
    char* uni = (char*)alloc((size_t)134217728);           // union region (lifetimes disjoint)
    u16* videob = (u16*)uni;                               // video bf16   [dead after video GEMM]
    u16* qb = (u16*)uni;                                   // q            [B,H,S,DH]
    u16* kb = (u16*)(uni + 33554432);                      // k            [B,H,S,DH]
    u16* vtb = (u16*)(uni + 67108864);                     // v^T          [B,H,DH,S]
    u16* ctxb = (u16*)(uni + 100663296);                   // ctx          [B,S,D]
    u16* hb = (u16*)uni;                                   // FFN hidden   [B,S,FF] (128 MB)

    dim3 tb(32, 8);

    probe_kernel<<<dim3(1), dim3(64), 0, stream>>>(pos_emb, flag);
    convert_kernel<<<dim3(8192), dim3(256), 0, stream>>>(video, videob, (long)Bb * Tt * FDd, flag);

    transpose_kernel<<<dim3(Dd / 32, FDd / 32), tb, 0, stream>>>(Wv, WvT, FDd, Dd, 0L, flag);
    for (int i = 0; i < NL; i++) {
        transpose_kernel<<<dim3(Dd / 32, Dd / 32), tb, 0, stream>>>(Wq, WqT[i], Dd, Dd, (long)i * Dd * Dd, flag);
        transpose_kernel<<<dim3(Dd / 32, Dd / 32), tb, 0, stream>>>(Wk, WkT[i], Dd, Dd, (long)i * Dd * Dd, flag);
        transpose_kernel<<<dim3(Dd / 32, Dd / 32), tb, 0, stream>>>(Wva, WvaT[i], Dd, Dd, (long)i * Dd * Dd, flag);
        transpose_kernel<<<dim3(Dd / 32, Dd / 32), tb, 0, stream>>>(Wo, WoT[i], Dd, Dd, (long)i * Dd * Dd, flag);
        transpose_kernel<<<dim3(FFf / 32, Dd / 32), tb, 0, stream>>>(W1, W1T[i], Dd, FFf, (long)i * Dd * FFf, flag);
        transpose_kernel<<<dim3(Dd / 32, FFf / 32), tb, 0, stream>>>(W2, W2T[i], FFf, Dd, (long)i * FFf * Dd, flag);
    }

    // video projection: [28672,1024] @ [1024,512] -> tmp fp32
    gemm_kernel<0><<<dim3(Dd / 128, (Bb * Tt) / 128), dim3(256), 0, stream>>>(
        videob, WvT, bv, 0L, tmp, Bb * Tt, Dd, FDd, flag);
    embed_kernel<<<dim3((Bb * Ss) / 4), dim3(256), 0, stream>>>(question, pos_emb, mod_emb, tmp,
                                                                nv_g, nv_b, emb_g, emb_b, x, flag);

    for (int i = 0; i < NL; i++) {
        gemm_kernel<2><<<dim3(4, 256), dim3(256), 0, stream>>>(x, WqT[i], bq, (long)i * Dd, qb,
                                                               Bb * Ss, Dd, Dd, flag);
        gemm_kernel<3><<<dim3(4, 256), dim3(256), 0, stream>>>(x, WkT[i], bk, (long)i * Dd, kb,
                                                               Bb * Ss, Dd, Dd, flag);
        gemm_kernel<4><<<dim3(4, 256), dim3(256), 0, stream>>>(x, WvaT[i], bva, (long)i * Dd, vtb,
                                                               Bb * Ss, Dd, Dd, flag);
        flash_kernel<<<dim3(Ss / 64, Hh, Bb), dim3(256), 0, stream>>>(qb, kb, vtb, mask, ctxb);
        gemm_kernel<0><<<dim3(4, 256), dim3(256), 0, stream>>>(ctxb, WoT[i], bo, (long)i * Dd, tmp,
                                                               Bb * Ss, Dd, Dd, flag);
        add_ln_kernel<<<dim3((Bb * Ss) / 4), dim3(256), 0, stream>>>(tmp, x, ln1_g, ln1_b,
                                                                     (long)i * Dd, x, 0, flag);
        gemm_kernel<1><<<dim3(16, 256), dim3(256), 0, stream>>>(x, W1T[i], b1, (long)i * FFf, hb,
                                                                Bb * Ss, FFf, Dd, flag);
        gemm_kernel<0><<<dim3(4, 256), dim3(256), 0, stream>>>(hb, W2T[i], b2, (long)i * Dd, tmp,
                                                               Bb * Ss, Dd, FFf, flag);
        void* dst = (i == NL - 1) ? d_out : (void*)x;
        add_ln_kernel<<<dim3((Bb * Ss) / 4), dim3(256), 0, stream>>>(
            tmp, x, ln2_g, ln2_b, (long)i * Dd, dst, (i == NL - 1) ? 1 : 0, flag);
    }
    (void)in_sizes; (void)n_in; (void)out_size; (void)ws_size;
}

// Round 2
// 1638.767 us; speedup vs baseline: 1.1264x; 1.1264x over previous
//
#include <hip/hip_runtime.h>
#include <hip/hip_bf16.h>
#include <stdint.h>

// Problem constants
#define Bb 64
#define Qq 64
#define Tt 448
#define Dd 512
#define FDd 1024
#define Hh 8
#define NL 2
#define FFf 2048
#define Ss 512
#define DHh 64

typedef unsigned short u16;
typedef __bf16 bf16x8 __attribute__((ext_vector_type(8)));
typedef float f32x4 __attribute__((ext_vector_type(4)));
typedef float fv4 __attribute__((ext_vector_type(4)));
typedef u16 u16x4 __attribute__((ext_vector_type(4)));

__device__ __forceinline__ float bf2f(u16 u) { return __uint_as_float(((uint32_t)u) << 16); }
__device__ __forceinline__ u16 f2bfu(float f) {
    uint32_t x = __float_as_uint(f);
    uint32_t r = x + 0x7FFFu + ((x >> 16) & 1u);
    return (u16)(r >> 16);
}
// Dual-mode load: input tensors may be bf16 (flag=1) or fp32 (flag=0)
__device__ __forceinline__ float ldx(const void* p, long i, int isbf) {
    return isbf ? bf2f(((const u16*)p)[i]) : ((const float*)p)[i];
}
__device__ __forceinline__ float geluf(float v) {
    return 0.5f * v * (1.0f + erff(v * 0.7071067811865475f));
}
// async global->LDS, 16B per lane; lds ptr must be wave-uniform base (HW adds lane*16)
__device__ __forceinline__ void gload16(const void* g, void* l) {
    __builtin_amdgcn_global_load_lds((const __attribute__((address_space(1))) void*)g,
                                     (__attribute__((address_space(3))) void*)l, 16, 0, 0);
}
#define MFMA16(a, b, c) __builtin_amdgcn_mfma_f32_16x16x32_bf16(a, b, c, 0, 0, 0)

// ---------------- dtype probe ----------------
// pos_emb[0,:2] = (sin0, cos0) = (0,1). bf16-packed word = 0x3F800000; fp32 word = 0.
__global__ void probe_kernel(const void* pos_emb, int* flag) {
    if (threadIdx.x == 0) {
        uint32_t w = *(const uint32_t*)pos_emb;
        *flag = (w == 0x3F800000u) ? 1 : 0;
    }
}

// ---------------- convert (video -> canonical bf16) ----------------
__global__ void convert_kernel(const void* __restrict__ src, u16* __restrict__ dst, long n,
                               const int* __restrict__ flag) {
    const int isbf = *flag;
    long i = (long)blockIdx.x * blockDim.x + threadIdx.x;
    long stride = (long)gridDim.x * blockDim.x;
    for (; i < n; i += stride) {
        dst[i] = isbf ? ((const u16*)src)[i] : f2bfu(((const float*)src)[i]);
    }
}

// ---------------- dual-mode weight transpose: W[R,C] -> Wt[C,R] (bf16 out) -------------
__global__ void transpose_kernel(const void* __restrict__ src, u16* __restrict__ dst,
                                 int R, int C, long elem_off, const int* __restrict__ flag) {
    __shared__ u16 tile[32][33];
    const int isbf = *flag;
    const int c0 = blockIdx.x * 32, r0 = blockIdx.y * 32;
    const int tx = threadIdx.x, ty = threadIdx.y;
#pragma unroll
    for (int i = 0; i < 32; i += 8) {
        long idx = elem_off + (long)(r0 + ty + i) * C + (c0 + tx);
        tile[ty + i][tx] = isbf ? ((const u16*)src)[idx] : f2bfu(((const float*)src)[idx]);
    }
    __syncthreads();
#pragma unroll
    for (int i = 0; i < 32; i += 8) {
        dst[(long)(c0 + ty + i) * R + (r0 + tx)] = tile[tx][ty + i];
    }
}

// ---------------- MFMA GEMM: C[M,N] = A[M,K] @ Bt[N,K]^T + bias, epilogue by MODE -------
// MODE 0: out fp32 [M,N]
// MODE 1: out bf16 [M,N], gelu
// MODE 2: out bf16 scatter [B,H,S,DH], scaled by 1/8 (q)
// MODE 3: out bf16 scatter [B,H,S,DH] (k)
// MODE 4: out bf16 scatter [B,H,DH,S] (v transposed)
template <int MODE>
__global__ __launch_bounds__(256) void gemm_kernel(const u16* __restrict__ A,
                                                   const u16* __restrict__ Bt,
                                                   const void* __restrict__ bias, long bias_off,
                                                   void* __restrict__ out, int M, int N, int K,
                                                   const int* __restrict__ flag) {
    __shared__ __align__(16) u16 sA[128 * 32];
    __shared__ __align__(16) u16 sB[128 * 32];
    const int tid = threadIdx.x;
    const int lane = tid & 63, wave = tid >> 6;
    const int wm = wave >> 1, wn = wave & 1;
    const int col16 = lane & 15, quad = lane >> 4;
    const long m0 = (long)blockIdx.y * 128;
    const long n0 = (long)blockIdx.x * 128;

    f32x4 acc[4][4];
#pragma unroll
    for (int i = 0; i < 4; i++)
#pragma unroll
        for (int j = 0; j < 4; j++) acc[i][j] = (f32x4){0.f, 0.f, 0.f, 0.f};

    for (int k0 = 0; k0 < K; k0 += 32) {
        __syncthreads();
#pragma unroll
        for (int i = 0; i < 2; i++) {
            int slot = tid + i * 256;
            int r = slot >> 2, kq = slot & 3;
            int lbase = (wave * 64 + i * 256) * 8;  // wave-uniform LDS base (elems)
            gload16(&A[(m0 + r) * K + k0 + kq * 8], &sA[lbase]);
            gload16(&Bt[(n0 + r) * K + k0 + kq * 8], &sB[lbase]);
        }
        __syncthreads();
        bf16x8 af[4], bfv[4];
#pragma unroll
        for (int mi = 0; mi < 4; mi++)
            af[mi] = *(const bf16x8*)&sA[(wm * 64 + mi * 16 + col16) * 32 + quad * 8];
#pragma unroll
        for (int ni = 0; ni < 4; ni++)
            bfv[ni] = *(const bf16x8*)&sB[(wn * 64 + ni * 16 + col16) * 32 + quad * 8];
#pragma unroll
        for (int mi = 0; mi < 4; mi++)
#pragma unroll
            for (int ni = 0; ni < 4; ni++)
                acc[mi][ni] = MFMA16(af[mi], bfv[ni], acc[mi][ni]);
    }

    const int isbf = *flag;
    float bb[4];
#pragma unroll
    for (int ni = 0; ni < 4; ni++)
        bb[ni] = ldx(bias, bias_off + n0 + wn * 64 + ni * 16 + col16, isbf);

#pragma unroll
    for (int mi = 0; mi < 4; mi++) {
#pragma unroll
        for (int ni = 0; ni < 4; ni++) {
            long col = n0 + wn * 64 + ni * 16 + col16;
#pragma unroll
            for (int r = 0; r < 4; r++) {
                long row = m0 + wm * 64 + mi * 16 + quad * 4 + r;
                float v = acc[mi][ni][r] + bb[ni];
                if (MODE == 0) {
                    ((float*)out)[row * N + col] = v;
                } else if (MODE == 1) {
                    ((u16*)out)[row * N + col] = f2bfu(geluf(v));
                } else if (MODE == 2 || MODE == 3) {
                    if (MODE == 2) v *= 0.125f;  // 1/sqrt(DH)
                    long b = row >> 9, s = row & 511;
                    long h = col >> 6, dh = col & 63;
                    ((u16*)out)[(((b * 8 + h) * 512) + s) * 64 + dh] = f2bfu(v);
                } else {  // MODE 4: v^T  [B,H,DH,S]
                    long b = row >> 9, s = row & 511;
                    long h = col >> 6, dh = col & 63;
                    ((u16*)out)[(((b * 8 + h) * 64) + dh) * 512 + s] = f2bfu(v);
                }
            }
        }
    }
}

// ---------------- wave-level LN helpers (one wave per row of 512) ----------------
__device__ __forceinline__ float wredsum(float v) {
#pragma unroll
    for (int off = 1; off < 64; off <<= 1) v += __shfl_xor(v, off);
    return v;
}
__device__ __forceinline__ void ln8(float v[8]) {
    float s = 0.f;
#pragma unroll
    for (int j = 0; j < 8; j++) s += v[j];
    s = wredsum(s);
    float m = s * (1.0f / 512.0f);
    float q = 0.f;
#pragma unroll
    for (int j = 0; j < 8; j++) {
        v[j] -= m;
        q += v[j] * v[j];
    }
    q = wredsum(q);
    float inv = rsqrtf(q * (1.0f / 512.0f) + 1e-12f);
#pragma unroll
    for (int j = 0; j < 8; j++) v[j] *= inv;
}

// ---------------- embed: concat(question, LN(videoproj)) + pos + mod, LN ---------------
__global__ __launch_bounds__(256) void embed_kernel(
    const void* __restrict__ question, const void* __restrict__ pos, const void* __restrict__ mod,
    const float* __restrict__ tmp, const void* __restrict__ nvg, const void* __restrict__ nvb,
    const void* __restrict__ eg, const void* __restrict__ eb, u16* __restrict__ x,
    const int* __restrict__ flag) {
    const int isbf = *flag;
    const int wave = threadIdx.x >> 6, lane = threadIdx.x & 63;
    const long row = (long)blockIdx.x * 4 + wave;
    const int b = (int)(row >> 9), s = (int)(row & 511);
    const int d0 = lane * 4, d1 = 256 + lane * 4;
    float v[8];
    if (s < Qq) {
        long base = ((long)b * Qq + s) * Dd;
#pragma unroll
        for (int j = 0; j < 4; j++) {
            v[j] = ldx(question, base + d0 + j, isbf);
            v[4 + j] = ldx(question, base + d1 + j, isbf);
        }
    } else {
        const float* tr = tmp + ((long)b * Tt + (s - Qq)) * Dd;
        fv4 f0 = *(const fv4*)(tr + d0);
        fv4 f1 = *(const fv4*)(tr + d1);
#pragma unroll
        for (int j = 0; j < 4; j++) {
            v[j] = f0[j];
            v[4 + j] = f1[j];
        }
        ln8(v);
#pragma unroll
        for (int j = 0; j < 4; j++) {
            v[j] = v[j] * ldx(nvg, d0 + j, isbf) + ldx(nvb, d0 + j, isbf);
            v[4 + j] = v[4 + j] * ldx(nvg, d1 + j, isbf) + ldx(nvb, d1 + j, isbf);
        }
    }
    const int mid = (s < Qq) ? 0 : 1;
#pragma unroll
    for (int j = 0; j < 4; j++) {
        v[j] += ldx(pos, (long)s * Dd + d0 + j, isbf) + ldx(mod, (long)mid * Dd + d0 + j, isbf);
        v[4 + j] += ldx(pos, (long)s * Dd + d1 + j, isbf) + ldx(mod, (long)mid * Dd + d1 + j, isbf);
    }
    ln8(v);
#pragma unroll
    for (int j = 0; j < 4; j++) {
        x[row * Dd + d0 + j] = f2bfu(v[j] * ldx(eg, d0 + j, isbf) + ldx(eb, d0 + j, isbf));
        x[row * Dd + d1 + j] = f2bfu(v[4 + j] * ldx(eg, d1 + j, isbf) + ldx(eb, d1 + j, isbf));
    }
}

// ---------------- add residual + LN ----------------
__global__ __launch_bounds__(256) void add_ln_kernel(const float* __restrict__ tmp,
                                                     const u16* __restrict__ xin,
                                                     const void* __restrict__ g,
                                                     const void* __restrict__ bta, long goff,
                                                     void* __restrict__ dst, int dst_is_final,
                                                     const int* __restrict__ flag) {
    const int isbf = *flag;
    const int wave = threadIdx.x >> 6, lane = threadIdx.x & 63;
    const long row = (long)blockIdx.x * 4 + wave;
    const int d0 = lane * 4, d1 = 256 + lane * 4;
    const float* tr = tmp + row * Dd;
    fv4 f0 = *(const fv4*)(tr + d0);
    fv4 f1 = *(const fv4*)(tr + d1);
    u16x4 x0 = *(const u16x4*)(xin + row * Dd + d0);
    u16x4 x1 = *(const u16x4*)(xin + row * Dd + d1);
    float v[8];
#pragma unroll
    for (int j = 0; j < 4; j++) {
        v[j] = f0[j] + bf2f(x0[j]);
        v[4 + j] = f1[j] + bf2f(x1[j]);
    }
    ln8(v);
#pragma unroll
    for (int j = 0; j < 8; j++) {
        int d = (j < 4) ? d0 + j : d1 + j - 4;
        v[j] = v[j] * ldx(g, goff + d, isbf) + ldx(bta, goff + d, isbf);
    }
    if (dst_is_final && !isbf) {
#pragma unroll
        for (int j = 0; j < 4; j++) {
            ((float*)dst)[row * Dd + d0 + j] = v[j];
            ((float*)dst)[row * Dd + d1 + j] = v[4 + j];
        }
    } else {
#pragma unroll
        for (int j = 0; j < 4; j++) {
            ((u16*)dst)[row * Dd + d0 + j] = f2bfu(v[j]);
            ((u16*)dst)[row * Dd + d1 + j] = f2bfu(v[4 + j]);
        }
    }
}

// ---------------- flash attention v2: LDS-staged K/V, 32 q-rows per wave ----------------
// q,k: [B,H,S,DH] bf16 (q pre-scaled); vT: [B,H,DH,S] bf16; ctx out: [B,S,D] bf16
// grid: 1D, bid = qt*512 + (b*8+h)  -> blocks sharing (b,h) land on same XCD (bid%8 const)
// LDS tiles XOR-swizzled (seg ^= row&7) so ds_read_b128 fragment reads sit at the b128 floor.
__global__ __launch_bounds__(256) void flash_kernel(const u16* __restrict__ q,
                                                    const u16* __restrict__ k,
                                                    const u16* __restrict__ vT,
                                                    const int* __restrict__ mask,
                                                    u16* __restrict__ ctx) {
    __shared__ __align__(16) u16 sK[64 * 64];        // 8 KB, chunk ci=(row*8+seg^..)
    __shared__ __align__(16) u16 sV[64 * 64];        // 8 KB
    __shared__ __align__(16) u16 pbuf[4][16 * 72];   // P transpose, stride 72 (pad)
    __shared__ int smask[Ss];

    const int tid = threadIdx.x;
    const int lane = tid & 63, wave = tid >> 6;
    const int col16 = lane & 15, quad = lane >> 4;
    const int bid = blockIdx.x;
    const int qt = bid >> 9;       // 0..3: 128-row q block
    const int bh = bid & 511;
    const int b = bh & 63, h = bh >> 6;
    const long bhl = (long)b * Hh + h;
    const u16* qp = q + bhl * Ss * DHh;
    const u16* kp = k + bhl * Ss * DHh;
    const u16* vp = vT + bhl * DHh * Ss;

    smask[tid] = mask[b * Ss + tid];
    smask[tid + 256] = mask[b * Ss + tid + 256];

    const int qbase = qt * 128 + wave * 32;
    bf16x8 aq[2][2];
#pragma unroll
    for (int t = 0; t < 2; t++) {
        aq[t][0] = *(const bf16x8*)&qp[(qbase + t * 16 + col16) * 64 + quad * 8];
        aq[t][1] = *(const bf16x8*)&qp[(qbase + t * 16 + col16) * 64 + 32 + quad * 8];
    }

    float mr[2][4], lr[2][4];
    f32x4 acc[2][4];
#pragma unroll
    for (int t = 0; t < 2; t++)
#pragma unroll
        for (int r = 0; r < 4; r++) {
            mr[t][r] = -__builtin_inff();
            lr[t][r] = 0.f;
        }
#pragma unroll
    for (int t = 0; t < 2; t++)
#pragma unroll
        for (int dt = 0; dt < 4; dt++) acc[t][dt] = (f32x4){0.f, 0.f, 0.f, 0.f};

    for (int c0 = 0; c0 < Ss; c0 += 64) {
        __syncthreads();  // previous iteration's LDS readers done
#pragma unroll
        for (int i = 0; i < 2; i++) {
            int ci = i * 256 + tid;
            int row = ci >> 3, sl = ci & 7;
            int sg = sl ^ (row & 7);  // xor swizzle on the GLOBAL side
            int lbase = (i * 256 + wave * 64) * 8;  // wave-uniform LDS base (elems)
            gload16(&kp[(c0 + row) * 64 + sg * 8], &sK[lbase]);
            gload16(&vp[row * 512 + c0 + sg * 8], &sV[lbase]);
        }
        __syncthreads();  // staging visible (compiler drains vmcnt before barrier)

        // K fragments for this 64-col tile (shared by both q-tiles)
        bf16x8 bk[4][2];
#pragma unroll
        for (int nt = 0; nt < 4; nt++) {
            int r = nt * 16 + col16;
            bk[nt][0] = *(const bf16x8*)&sK[(r * 8 + (quad ^ (r & 7))) * 8];
            bk[nt][1] = *(const bf16x8*)&sK[(r * 8 + ((4 + quad) ^ (r & 7))) * 8];
        }

#pragma unroll
        for (int t = 0; t < 2; t++) {
            f32x4 sc[4];
#pragma unroll
            for (int nt = 0; nt < 4; nt++) {
                f32x4 z = (f32x4){0.f, 0.f, 0.f, 0.f};
                z = MFMA16(aq[t][0], bk[nt][0], z);
                z = MFMA16(aq[t][1], bk[nt][1], z);
                if (smask[c0 + nt * 16 + col16] == 0) {
#pragma unroll
                    for (int r = 0; r < 4; r++) z[r] = -__builtin_inff();
                }
                sc[nt] = z;
            }
            float alpha[4];
#pragma unroll
            for (int r = 0; r < 4; r++) {
                float cm = fmaxf(fmaxf(sc[0][r], sc[1][r]), fmaxf(sc[2][r], sc[3][r]));
#pragma unroll
                for (int off = 1; off < 16; off <<= 1) cm = fmaxf(cm, __shfl_xor(cm, off));
                float mn = fmaxf(mr[t][r], cm);
                alpha[r] = (mr[t][r] >= mn) ? 1.0f : __expf(mr[t][r] - mn);
                float rsum = 0.f;
#pragma unroll
                for (int nt = 0; nt < 4; nt++) {
                    float p = sc[nt][r];
                    p = (p == -__builtin_inff()) ? 0.f : __expf(p - mn);
                    rsum += p;
                    pbuf[wave][(quad * 4 + r) * 72 + nt * 16 + col16] = f2bfu(p);
                }
#pragma unroll
                for (int off = 1; off < 16; off <<= 1) rsum += __shfl_xor(rsum, off);
                lr[t][r] = lr[t][r] * alpha[r] + rsum;
                mr[t][r] = mn;
            }
#pragma unroll
            for (int dt = 0; dt < 4; dt++) {
#pragma unroll
                for (int r = 0; r < 4; r++) acc[t][dt][r] *= alpha[r];
            }
            // P (C-layout) -> A-operand layout via per-wave LDS (same-wave DS is in-order)
#pragma unroll
            for (int hf = 0; hf < 2; hf++) {
                bf16x8 ap = *(const bf16x8*)&pbuf[wave][col16 * 72 + hf * 32 + quad * 8];
#pragma unroll
                for (int dt = 0; dt < 4; dt++) {
                    int d = dt * 16 + col16;
                    bf16x8 bv = *(const bf16x8*)&sV[(d * 8 + ((hf * 4 + quad) ^ (d & 7))) * 8];
                    acc[t][dt] = MFMA16(ap, bv, acc[t][dt]);
                }
            }
        }
    }
#pragma unroll
    for (int t = 0; t < 2; t++)
#pragma unroll
        for (int dt = 0; dt < 4; dt++) {
#pragma unroll
            for (int r = 0; r < 4; r++) {
                float v = acc[t][dt][r] / lr[t][r];
                int sq = qbase + t * 16 + quad * 4 + r;
                int d = h * 64 + dt * 16 + col16;
                ctx[((long)b * Ss + sq) * Dd + d] = f2bfu(v);
            }
        }
}

// ---------------- host ----------------
extern "C" void kernel_launch(void* const* d_in, const int* in_sizes, int n_in, void* d_out,
                              int out_size, void* d_ws, size_t ws_size, hipStream_t stream) {
    const void* video = d_in[0];
    const void* question = d_in[1];
    const int* mask = (const int*)d_in[2];
    const void* pos_emb = d_in[3];
    const void* mod_emb = d_in[4];
    const void* Wv = d_in[5];
    const void* bv = d_in[6];
    const void* nv_g = d_in[7];
    const void* nv_b = d_in[8];
    const void* emb_g = d_in[9];
    const void* emb_b = d_in[10];
    const void* Wq = d_in[11];
    const void* bq = d_in[12];
    const void* Wk = d_in[13];
    const void* bk = d_in[14];
    const void* Wva = d_in[15];
    const void* bva = d_in[16];
    const void* Wo = d_in[17];
    const void* bo = d_in[18];
    const void* ln1_g = d_in[19];
    const void* ln1_b = d_in[20];
    const void* W1 = d_in[21];
    const void* b1 = d_in[22];
    const void* W2 = d_in[23];
    const void* b2 = d_in[24];
    const void* ln2_g = d_in[25];
    const void* ln2_b = d_in[26];

    char* wsb = (char*)d_ws;
    size_t off = 0;
    auto alloc = [&](size_t bytes) -> void* {
        void* p = (void*)(wsb + off);
        off += (bytes + 4095) & ~((size_t)4095);
        return p;
    };
    int* flag = (int*)alloc(16);
    u16* WvT = (u16*)alloc((size_t)Dd * FDd * 2);
    u16 *WqT[NL], *WkT[NL], *WvaT[NL], *WoT[NL], *W1T[NL], *W2T[NL];
    for (int i = 0; i < NL; i++) {
        WqT[i] = (u16*)alloc((size_t)Dd * Dd * 2);
        WkT[i] = (u16*)alloc((size_t)Dd * Dd * 2);
        WvaT[i] = (u16*)alloc((size_t)Dd * Dd * 2);
        WoT[i] = (u16*)alloc((size_t)Dd * Dd * 2);
        W1T[i] = (u16*)alloc((size_t)FFf * Dd * 2);
        W2T[i] = (u16*)alloc((size_t)Dd * FFf * 2);
    }
    u16* x = (u16*)alloc((size_t)Bb * Ss * Dd * 2);      // 32 MB residual stream (bf16)
    float* tmp = (float*)alloc((size_t)Bb * Ss * Dd * 4);  // 64 MB fp32 GEMM out
    char* uni = (char*)alloc((size_t)134217728);           // union region (lifetimes disjoint)
    u16* videob = (u16*)uni;                               // video bf16   [dead after video GEMM]
    u16* qb = (u16*)uni;                                   // q            [B,H,S,DH]
    u16* kb = (u16*)(uni + 33554432);                      // k            [B,H,S,DH]
    u16* vtb = (u16*)(uni + 67108864);                     // v^T          [B,H,DH,S]
    u16* ctxb = (u16*)(uni + 100663296);                   // ctx          [B,S,D]
    u16* hb = (u16*)uni;                                   // FFN hidden   [B,S,FF] (128 MB)

    dim3 tb(32, 8);

    probe_kernel<<<dim3(1), dim3(64), 0, stream>>>(pos_emb, flag);
    convert_kernel<<<dim3(8192), dim3(256), 0, stream>>>(video, videob, (long)Bb * Tt * FDd, flag);

    transpose_kernel<<<dim3(Dd / 32, FDd / 32), tb, 0, stream>>>(Wv, WvT, FDd, Dd, 0L, flag);
    for (int i = 0; i < NL; i++) {
        transpose_kernel<<<dim3(Dd / 32, Dd / 32), tb, 0, stream>>>(Wq, WqT[i], Dd, Dd, (long)i * Dd * Dd, flag);
        transpose_kernel<<<dim3(Dd / 32, Dd / 32), tb, 0, stream>>>(Wk, WkT[i], Dd, Dd, (long)i * Dd * Dd, flag);
        transpose_kernel<<<dim3(Dd / 32, Dd / 32), tb, 0, stream>>>(Wva, WvaT[i], Dd, Dd, (long)i * Dd * Dd, flag);
        transpose_kernel<<<dim3(Dd / 32, Dd / 32), tb, 0, stream>>>(Wo, WoT[i], Dd, Dd, (long)i * Dd * Dd, flag);
        transpose_kernel<<<dim3(FFf / 32, Dd / 32), tb, 0, stream>>>(W1, W1T[i], Dd, FFf, (long)i * Dd * FFf, flag);
        transpose_kernel<<<dim3(Dd / 32, FFf / 32), tb, 0, stream>>>(W2, W2T[i], FFf, Dd, (long)i * FFf * Dd, flag);
    }

    // video projection: [28672,1024] @ [1024,512] -> tmp fp32
    gemm_kernel<0><<<dim3(Dd / 128, (Bb * Tt) / 128), dim3(256), 0, stream>>>(
        videob, WvT, bv, 0L, tmp, Bb * Tt, Dd, FDd, flag);
    embed_kernel<<<dim3((Bb * Ss) / 4), dim3(256), 0, stream>>>(question, pos_emb, mod_emb, tmp,
                                                                nv_g, nv_b, emb_g, emb_b, x, flag);

    for (int i = 0; i < NL; i++) {
        gemm_kernel<2><<<dim3(4, 256), dim3(256), 0, stream>>>(x, WqT[i], bq, (long)i * Dd, qb,
                                                               Bb * Ss, Dd, Dd, flag);
        gemm_kernel<3><<<dim3(4, 256), dim3(256), 0, stream>>>(x, WkT[i], bk, (long)i * Dd, kb,
                                                               Bb * Ss, Dd, Dd, flag);
        gemm_kernel<4><<<dim3(4, 256), dim3(256), 0, stream>>>(x, WvaT[i], bva, (long)i * Dd, vtb,
                                                               Bb * Ss, Dd, Dd, flag);
        flash_kernel<<<dim3(2048), dim3(256), 0, stream>>>(qb, kb, vtb, mask, ctxb);
        gemm_kernel<0><<<dim3(4, 256), dim3(256), 0, stream>>>(ctxb, WoT[i], bo, (long)i * Dd, tmp,
                                                               Bb * Ss, Dd, Dd, flag);
        add_ln_kernel<<<dim3((Bb * Ss) / 4), dim3(256), 0, stream>>>(tmp, x, ln1_g, ln1_b,
                                                                     (long)i * Dd, x, 0, flag);
        gemm_kernel<1><<<dim3(16, 256), dim3(256), 0, stream>>>(x, W1T[i], b1, (long)i * FFf, hb,
                                                                Bb * Ss, FFf, Dd, flag);
        gemm_kernel<0><<<dim3(4, 256), dim3(256), 0, stream>>>(hb, W2T[i], b2, (long)i * Dd, tmp,
                                                               Bb * Ss, Dd, FFf, flag);
        void* dst = (i == NL - 1) ? d_out : (void*)x;
        add_ln_kernel<<<dim3((Bb * Ss) / 4), dim3(256), 0, stream>>>(
            tmp, x, ln2_g, ln2_b, (long)i * Dd, dst, (i == NL - 1) ? 1 : 0, flag);
    }
    (void)in_sizes; (void)n_in; (void)out_size; (void)ws_size;
}

// Round 3
// 1575.278 us; speedup vs baseline: 1.1718x; 1.0403x over previous
//
#include <hip/hip_runtime.h>
#include <hip/hip_bf16.h>
#include <stdint.h>

// Problem constants
#define Bb 64
#define Qq 64
#define Tt 448
#define Dd 512
#define FDd 1024
#define Hh 8
#define NL 2
#define FFf 2048
#define Ss 512
#define DHh 64

typedef unsigned short u16;
typedef __bf16 bf16x8 __attribute__((ext_vector_type(8)));
typedef float f32x4 __attribute__((ext_vector_type(4)));
typedef float fv4 __attribute__((ext_vector_type(4)));
typedef u16 u16x4 __attribute__((ext_vector_type(4)));

__device__ __forceinline__ float bf2f(u16 u) { return __uint_as_float(((uint32_t)u) << 16); }
// native RNE f32->bf16 (gfx950 has v_cvt_pk_bf16_f32; clang lowers fptrunc to it)
__device__ __forceinline__ u16 f2bfu(float f) {
    __bf16 h = (__bf16)f;
    return __builtin_bit_cast(unsigned short, h);
}
// Dual-mode load: input tensors may be bf16 (flag=1) or fp32 (flag=0)
__device__ __forceinline__ float ldx(const void* p, long i, int isbf) {
    return isbf ? bf2f(((const u16*)p)[i]) : ((const float*)p)[i];
}
__device__ __forceinline__ float geluf(float v) {
    return 0.5f * v * (1.0f + erff(v * 0.7071067811865475f));
}
// async global->LDS, 16B per lane; lds ptr must be wave-uniform base (HW adds lane*16)
__device__ __forceinline__ void gload16(const void* g, void* l) {
    __builtin_amdgcn_global_load_lds((const __attribute__((address_space(1))) void*)g,
                                     (__attribute__((address_space(3))) void*)l, 16, 0, 0);
}
#define MFMA16(a, b, c) __builtin_amdgcn_mfma_f32_16x16x32_bf16(a, b, c, 0, 0, 0)

// ---------------- dtype probe ----------------
// pos_emb[0,:2] = (sin0, cos0) = (0,1). bf16-packed word = 0x3F800000; fp32 word = 0.
__global__ void probe_kernel(const void* pos_emb, int* flag) {
    if (threadIdx.x == 0) {
        uint32_t w = *(const uint32_t*)pos_emb;
        *flag = (w == 0x3F800000u) ? 1 : 0;
    }
}

// ---------------- convert (video -> canonical bf16) ----------------
__global__ void convert_kernel(const void* __restrict__ src, u16* __restrict__ dst, long n,
                               const int* __restrict__ flag) {
    const int isbf = *flag;
    long i = (long)blockIdx.x * blockDim.x + threadIdx.x;
    long stride = (long)gridDim.x * blockDim.x;
    for (; i < n; i += stride) {
        dst[i] = isbf ? ((const u16*)src)[i] : f2bfu(((const float*)src)[i]);
    }
}

// ---------------- dual-mode weight transpose: W[R,C] -> Wt[C,R] (bf16 out) -------------
__global__ void transpose_kernel(const void* __restrict__ src, u16* __restrict__ dst,
                                 int R, int C, long elem_off, const int* __restrict__ flag) {
    __shared__ u16 tile[32][33];
    const int isbf = *flag;
    const int c0 = blockIdx.x * 32, r0 = blockIdx.y * 32;
    const int tx = threadIdx.x, ty = threadIdx.y;
#pragma unroll
    for (int i = 0; i < 32; i += 8) {
        long idx = elem_off + (long)(r0 + ty + i) * C + (c0 + tx);
        tile[ty + i][tx] = isbf ? ((const u16*)src)[idx] : f2bfu(((const float*)src)[idx]);
    }
    __syncthreads();
#pragma unroll
    for (int i = 0; i < 32; i += 8) {
        dst[(long)(c0 + ty + i) * R + (r0 + tx)] = tile[tx][ty + i];
    }
}

// ---------------- MFMA GEMM: C[M,N] = A[M,K] @ Bt[N,K]^T + bias -------
// MODE 0: out bf16 [M,N]
// MODE 1: out bf16 [M,N], gelu
template <int MODE>
__global__ __launch_bounds__(256) void gemm_kernel(const u16* __restrict__ A,
                                                   const u16* __restrict__ Bt,
                                                   const void* __restrict__ bias, long bias_off,
                                                   void* __restrict__ out, int M, int N, int K,
                                                   const int* __restrict__ flag) {
    __shared__ __align__(16) u16 sA[128 * 32];
    __shared__ __align__(16) u16 sB[128 * 32];
    const int tid = threadIdx.x;
    const int lane = tid & 63, wave = tid >> 6;
    const int wm = wave >> 1, wn = wave & 1;
    const int col16 = lane & 15, quad = lane >> 4;
    const long m0 = (long)blockIdx.y * 128;
    const long n0 = (long)blockIdx.x * 128;

    f32x4 acc[4][4];
#pragma unroll
    for (int i = 0; i < 4; i++)
#pragma unroll
        for (int j = 0; j < 4; j++) acc[i][j] = (f32x4){0.f, 0.f, 0.f, 0.f};

    for (int k0 = 0; k0 < K; k0 += 32) {
        __syncthreads();
#pragma unroll
        for (int i = 0; i < 2; i++) {
            int slot = tid + i * 256;
            int r = slot >> 2, kq = slot & 3;
            int lbase = (wave * 64 + i * 256) * 8;  // wave-uniform LDS base (elems)
            gload16(&A[(m0 + r) * K + k0 + kq * 8], &sA[lbase]);
            gload16(&Bt[(n0 + r) * K + k0 + kq * 8], &sB[lbase]);
        }
        __syncthreads();
        bf16x8 af[4], bfv[4];
#pragma unroll
        for (int mi = 0; mi < 4; mi++)
            af[mi] = *(const bf16x8*)&sA[(wm * 64 + mi * 16 + col16) * 32 + quad * 8];
#pragma unroll
        for (int ni = 0; ni < 4; ni++)
            bfv[ni] = *(const bf16x8*)&sB[(wn * 64 + ni * 16 + col16) * 32 + quad * 8];
#pragma unroll
        for (int mi = 0; mi < 4; mi++)
#pragma unroll
            for (int ni = 0; ni < 4; ni++)
                acc[mi][ni] = MFMA16(af[mi], bfv[ni], acc[mi][ni]);
    }

    const int isbf = *flag;
    float bb[4];
#pragma unroll
    for (int ni = 0; ni < 4; ni++)
        bb[ni] = ldx(bias, bias_off + n0 + wn * 64 + ni * 16 + col16, isbf);

#pragma unroll
    for (int mi = 0; mi < 4; mi++) {
#pragma unroll
        for (int ni = 0; ni < 4; ni++) {
            long col = n0 + wn * 64 + ni * 16 + col16;
#pragma unroll
            for (int r = 0; r < 4; r++) {
                long row = m0 + wm * 64 + mi * 16 + quad * 4 + r;
                float v = acc[mi][ni][r] + bb[ni];
                if (MODE == 0) {
                    ((u16*)out)[row * N + col] = f2bfu(v);
                } else {
                    ((u16*)out)[row * N + col] = f2bfu(geluf(v));
                }
            }
        }
    }
}

// ---------------- fused QKV GEMM: A[M,512] @ WqkvT[1536,512]^T, scatter epilogue --------
// WqkvT rows 0-511 = Wq^T, 512-1023 = Wk^T, 1024-1535 = Wva^T. 128-col blocks never
// straddle a 512 boundary -> region is block-uniform.
__global__ __launch_bounds__(256) void qkv_kernel(const u16* __restrict__ A,
                                                  const u16* __restrict__ Bt,
                                                  const void* __restrict__ bq,
                                                  const void* __restrict__ bk,
                                                  const void* __restrict__ bva, long boff,
                                                  u16* __restrict__ qb, u16* __restrict__ kb,
                                                  u16* __restrict__ vtb,
                                                  const int* __restrict__ flag) {
    __shared__ __align__(16) u16 sA[128 * 32];
    __shared__ __align__(16) u16 sB[128 * 32];
    const int tid = threadIdx.x;
    const int lane = tid & 63, wave = tid >> 6;
    const int wm = wave >> 1, wn = wave & 1;
    const int col16 = lane & 15, quad = lane >> 4;
    const long m0 = (long)blockIdx.y * 128;
    const long n0 = (long)blockIdx.x * 128;
    const int K = Dd;

    f32x4 acc[4][4];
#pragma unroll
    for (int i = 0; i < 4; i++)
#pragma unroll
        for (int j = 0; j < 4; j++) acc[i][j] = (f32x4){0.f, 0.f, 0.f, 0.f};

    for (int k0 = 0; k0 < K; k0 += 32) {
        __syncthreads();
#pragma unroll
        for (int i = 0; i < 2; i++) {
            int slot = tid + i * 256;
            int r = slot >> 2, kq = slot & 3;
            int lbase = (wave * 64 + i * 256) * 8;
            gload16(&A[(m0 + r) * K + k0 + kq * 8], &sA[lbase]);
            gload16(&Bt[(n0 + r) * K + k0 + kq * 8], &sB[lbase]);
        }
        __syncthreads();
        bf16x8 af[4], bfv[4];
#pragma unroll
        for (int mi = 0; mi < 4; mi++)
            af[mi] = *(const bf16x8*)&sA[(wm * 64 + mi * 16 + col16) * 32 + quad * 8];
#pragma unroll
        for (int ni = 0; ni < 4; ni++)
            bfv[ni] = *(const bf16x8*)&sB[(wn * 64 + ni * 16 + col16) * 32 + quad * 8];
#pragma unroll
        for (int mi = 0; mi < 4; mi++)
#pragma unroll
            for (int ni = 0; ni < 4; ni++)
                acc[mi][ni] = MFMA16(af[mi], bfv[ni], acc[mi][ni]);
    }

    const int isbf = *flag;
    const int region = (int)(n0 >> 9);  // 0=q, 1=k, 2=v (block-uniform)
    const void* bias = (region == 0) ? bq : (region == 1) ? bk : bva;
    float bb[4];
#pragma unroll
    for (int ni = 0; ni < 4; ni++) {
        long col = n0 + wn * 64 + ni * 16 + col16;
        bb[ni] = ldx(bias, boff + (col & 511), isbf);
    }

#pragma unroll
    for (int mi = 0; mi < 4; mi++) {
#pragma unroll
        for (int ni = 0; ni < 4; ni++) {
            long col = n0 + wn * 64 + ni * 16 + col16;
            long cc = col & 511;
            long h = cc >> 6, dh = cc & 63;
            long row0 = m0 + wm * 64 + mi * 16 + quad * 4;
            long b = row0 >> 9, s0 = row0 & 511;
            if (region == 0) {
#pragma unroll
                for (int r = 0; r < 4; r++)
                    qb[(((b * 8 + h) * 512) + s0 + r) * 64 + dh] =
                        f2bfu((acc[mi][ni][r] + bb[ni]) * 0.125f);
            } else if (region == 1) {
#pragma unroll
                for (int r = 0; r < 4; r++)
                    kb[(((b * 8 + h) * 512) + s0 + r) * 64 + dh] = f2bfu(acc[mi][ni][r] + bb[ni]);
            } else {  // v^T: 4 consecutive s for fixed dh -> one 8B store
                u16x4 pk;
#pragma unroll
                for (int r = 0; r < 4; r++) pk[r] = f2bfu(acc[mi][ni][r] + bb[ni]);
                *(u16x4*)&vtb[(((b * 8 + h) * 64) + dh) * 512 + s0] = pk;
            }
        }
    }
}

// ---------------- wave-level LN helpers (one wave per row of 512) ----------------
__device__ __forceinline__ float wredsum(float v) {
#pragma unroll
    for (int off = 1; off < 64; off <<= 1) v += __shfl_xor(v, off);
    return v;
}
__device__ __forceinline__ void ln8(float v[8]) {
    float s = 0.f;
#pragma unroll
    for (int j = 0; j < 8; j++) s += v[j];
    s = wredsum(s);
    float m = s * (1.0f / 512.0f);
    float q = 0.f;
#pragma unroll
    for (int j = 0; j < 8; j++) {
        v[j] -= m;
        q += v[j] * v[j];
    }
    q = wredsum(q);
    float inv = rsqrtf(q * (1.0f / 512.0f) + 1e-12f);
#pragma unroll
    for (int j = 0; j < 8; j++) v[j] *= inv;
}

// ---------------- embed: concat(question, LN(videoproj)) + pos + mod, LN ---------------
__global__ __launch_bounds__(256) void embed_kernel(
    const void* __restrict__ question, const void* __restrict__ pos, const void* __restrict__ mod,
    const u16* __restrict__ tmp, const void* __restrict__ nvg, const void* __restrict__ nvb,
    const void* __restrict__ eg, const void* __restrict__ eb, u16* __restrict__ x,
    const int* __restrict__ flag) {
    const int isbf = *flag;
    const int wave = threadIdx.x >> 6, lane = threadIdx.x & 63;
    const long row = (long)blockIdx.x * 4 + wave;
    const int b = (int)(row >> 9), s = (int)(row & 511);
    const int d0 = lane * 4, d1 = 256 + lane * 4;
    float v[8];
    if (s < Qq) {
        long base = ((long)b * Qq + s) * Dd;
#pragma unroll
        for (int j = 0; j < 4; j++) {
            v[j] = ldx(question, base + d0 + j, isbf);
            v[4 + j] = ldx(question, base + d1 + j, isbf);
        }
    } else {
        const u16* tr = tmp + ((long)b * Tt + (s - Qq)) * Dd;
        u16x4 f0 = *(const u16x4*)(tr + d0);
        u16x4 f1 = *(const u16x4*)(tr + d1);
#pragma unroll
        for (int j = 0; j < 4; j++) {
            v[j] = bf2f(f0[j]);
            v[4 + j] = bf2f(f1[j]);
        }
        ln8(v);
#pragma unroll
        for (int j = 0; j < 4; j++) {
            v[j] = v[j] * ldx(nvg, d0 + j, isbf) + ldx(nvb, d0 + j, isbf);
            v[4 + j] = v[4 + j] * ldx(nvg, d1 + j, isbf) + ldx(nvb, d1 + j, isbf);
        }
    }
    const int mid = (s < Qq) ? 0 : 1;
#pragma unroll
    for (int j = 0; j < 4; j++) {
        v[j] += ldx(pos, (long)s * Dd + d0 + j, isbf) + ldx(mod, (long)mid * Dd + d0 + j, isbf);
        v[4 + j] += ldx(pos, (long)s * Dd + d1 + j, isbf) + ldx(mod, (long)mid * Dd + d1 + j, isbf);
    }
    ln8(v);
#pragma unroll
    for (int j = 0; j < 4; j++) {
        x[row * Dd + d0 + j] = f2bfu(v[j] * ldx(eg, d0 + j, isbf) + ldx(eb, d0 + j, isbf));
        x[row * Dd + d1 + j] = f2bfu(v[4 + j] * ldx(eg, d1 + j, isbf) + ldx(eb, d1 + j, isbf));
    }
}

// ---------------- add residual + LN (tmp is bf16 now) ----------------
__global__ __launch_bounds__(256) void add_ln_kernel(const u16* __restrict__ tmp,
                                                     const u16* __restrict__ xin,
                                                     const void* __restrict__ g,
                                                     const void* __restrict__ bta, long goff,
                                                     void* __restrict__ dst, int dst_is_final,
                                                     const int* __restrict__ flag) {
    const int isbf = *flag;
    const int wave = threadIdx.x >> 6, lane = threadIdx.x & 63;
    const long row = (long)blockIdx.x * 4 + wave;
    const int d0 = lane * 4, d1 = 256 + lane * 4;
    u16x4 t0 = *(const u16x4*)(tmp + row * Dd + d0);
    u16x4 t1 = *(const u16x4*)(tmp + row * Dd + d1);
    u16x4 x0 = *(const u16x4*)(xin + row * Dd + d0);
    u16x4 x1 = *(const u16x4*)(xin + row * Dd + d1);
    float v[8];
#pragma unroll
    for (int j = 0; j < 4; j++) {
        v[j] = bf2f(t0[j]) + bf2f(x0[j]);
        v[4 + j] = bf2f(t1[j]) + bf2f(x1[j]);
    }
    ln8(v);
#pragma unroll
    for (int j = 0; j < 8; j++) {
        int d = (j < 4) ? d0 + j : d1 + j - 4;
        v[j] = v[j] * ldx(g, goff + d, isbf) + ldx(bta, goff + d, isbf);
    }
    if (dst_is_final && !isbf) {
#pragma unroll
        for (int j = 0; j < 4; j++) {
            ((float*)dst)[row * Dd + d0 + j] = v[j];
            ((float*)dst)[row * Dd + d1 + j] = v[4 + j];
        }
    } else {
#pragma unroll
        for (int j = 0; j < 4; j++) {
            ((u16*)dst)[row * Dd + d0 + j] = f2bfu(v[j]);
            ((u16*)dst)[row * Dd + d1 + j] = f2bfu(v[4 + j]);
        }
    }
}

// ---------------- flash attention v3: LDS-staged K/V, MFMA row-sums, native bf16 cvt ----
// q,k: [B,H,S,DH] bf16 (q pre-scaled); vT: [B,H,DH,S] bf16; ctx out: [B,S,D] bf16
// grid: 1D, bid = qt*512 + bh -> blocks sharing (b,h) on same XCD (bid%8 const).
// Online softmax with deferred normalization: l accumulated as P@1 via an extra MFMA.
__global__ __launch_bounds__(256) void flash_kernel(const u16* __restrict__ q,
                                                    const u16* __restrict__ k,
                                                    const u16* __restrict__ vT,
                                                    const int* __restrict__ mask,
                                                    u16* __restrict__ ctx) {
    __shared__ __align__(16) u16 sK[64 * 64];
    __shared__ __align__(16) u16 sV[64 * 64];
    __shared__ __align__(16) u16 pbuf[4][16 * 72];
    __shared__ float smaskf[Ss];

    const int tid = threadIdx.x;
    const int lane = tid & 63, wave = tid >> 6;
    const int col16 = lane & 15, quad = lane >> 4;
    const int bid = blockIdx.x;
    const int qt = bid >> 9;
    const int bh = bid & 511;
    const int b = bh & 63, h = bh >> 6;
    const long bhl = (long)b * Hh + h;
    const u16* qp = q + bhl * Ss * DHh;
    const u16* kp = k + bhl * Ss * DHh;
    const u16* vp = vT + bhl * DHh * Ss;

    smaskf[tid] = mask[b * Ss + tid] ? 0.f : -1e30f;
    smaskf[tid + 256] = mask[b * Ss + tid + 256] ? 0.f : -1e30f;

    const int qbase = qt * 128 + wave * 32;
    bf16x8 aq[2][2];
#pragma unroll
    for (int t = 0; t < 2; t++) {
        aq[t][0] = *(const bf16x8*)&qp[(qbase + t * 16 + col16) * 64 + quad * 8];
        aq[t][1] = *(const bf16x8*)&qp[(qbase + t * 16 + col16) * 64 + 32 + quad * 8];
    }

    bf16x8 vone;
#pragma unroll
    for (int j = 0; j < 8; j++) vone[j] = (__bf16)1.0f;

    float mr[2][4];
    f32x4 acc[2][4], accl[2];
#pragma unroll
    for (int t = 0; t < 2; t++) {
        accl[t] = (f32x4){0.f, 0.f, 0.f, 0.f};
#pragma unroll
        for (int r = 0; r < 4; r++) mr[t][r] = -1e30f;
#pragma unroll
        for (int dt = 0; dt < 4; dt++) acc[t][dt] = (f32x4){0.f, 0.f, 0.f, 0.f};
    }

    for (int c0 = 0; c0 < Ss; c0 += 64) {
        __syncthreads();
#pragma unroll
        for (int i = 0; i < 2; i++) {
            int ci = i * 256 + tid;
            int row = ci >> 3, sl = ci & 7;
            int sg = sl ^ (row & 7);  // xor swizzle on the GLOBAL side
            int lbase = (i * 256 + wave * 64) * 8;
            gload16(&kp[(c0 + row) * 64 + sg * 8], &sK[lbase]);
            gload16(&vp[row * 512 + c0 + sg * 8], &sV[lbase]);
        }
        __syncthreads();

        bf16x8 bk[4][2];
#pragma unroll
        for (int nt = 0; nt < 4; nt++) {
            int r = nt * 16 + col16;
            bk[nt][0] = *(const bf16x8*)&sK[(r * 8 + (quad ^ (r & 7))) * 8];
            bk[nt][1] = *(const bf16x8*)&sK[(r * 8 + ((4 + quad) ^ (r & 7))) * 8];
        }

#pragma unroll
        for (int t = 0; t < 2; t++) {
            f32x4 sc[4];
#pragma unroll
            for (int nt = 0; nt < 4; nt++) {
                f32x4 z = (f32x4){0.f, 0.f, 0.f, 0.f};
                z = MFMA16(aq[t][0], bk[nt][0], z);
                z = MFMA16(aq[t][1], bk[nt][1], z);
                float mf = smaskf[c0 + nt * 16 + col16];
#pragma unroll
                for (int r = 0; r < 4; r++) z[r] += mf;
                sc[nt] = z;
            }
            float alpha[4];
#pragma unroll
            for (int r = 0; r < 4; r++) {
                float cm = fmaxf(fmaxf(sc[0][r], sc[1][r]), fmaxf(sc[2][r], sc[3][r]));
#pragma unroll
                for (int off = 1; off < 16; off <<= 1) cm = fmaxf(cm, __shfl_xor(cm, off));
                float mn = fmaxf(mr[t][r], cm);
                alpha[r] = __expf(mr[t][r] - mn);  // mr<=mn always; ==0 on first chunk
                mr[t][r] = mn;
#pragma unroll
                for (int nt = 0; nt < 4; nt++)
                    pbuf[wave][(quad * 4 + r) * 72 + nt * 16 + col16] =
                        f2bfu(__expf(sc[nt][r] - mn));
            }
#pragma unroll
            for (int dt = 0; dt < 4; dt++) {
#pragma unroll
                for (int r = 0; r < 4; r++) acc[t][dt][r] *= alpha[r];
            }
#pragma unroll
            for (int r = 0; r < 4; r++) accl[t][r] *= alpha[r];
            // P (C-layout) -> A-operand layout via per-wave LDS (same-wave DS is in-order)
#pragma unroll
            for (int hf = 0; hf < 2; hf++) {
                bf16x8 ap = *(const bf16x8*)&pbuf[wave][col16 * 72 + hf * 32 + quad * 8];
#pragma unroll
                for (int dt = 0; dt < 4; dt++) {
                    int d = dt * 16 + col16;
                    bf16x8 bv = *(const bf16x8*)&sV[(d * 8 + ((hf * 4 + quad) ^ (d & 7))) * 8];
                    acc[t][dt] = MFMA16(ap, bv, acc[t][dt]);
                }
                accl[t] = MFMA16(ap, vone, accl[t]);  // row-sum column (deferred l)
            }
        }
    }
#pragma unroll
    for (int t = 0; t < 2; t++)
#pragma unroll
        for (int dt = 0; dt < 4; dt++) {
#pragma unroll
            for (int r = 0; r < 4; r++) {
                float v = acc[t][dt][r] / accl[t][r];
                int sq = qbase + t * 16 + quad * 4 + r;
                int d = h * 64 + dt * 16 + col16;
                ctx[((long)b * Ss + sq) * Dd + d] = f2bfu(v);
            }
        }
}

// ---------------- host ----------------
extern "C" void kernel_launch(void* const* d_in, const int* in_sizes, int n_in, void* d_out,
                              int out_size, void* d_ws, size_t ws_size, hipStream_t stream) {
    const void* video = d_in[0];
    const void* question = d_in[1];
    const int* mask = (const int*)d_in[2];
    const void* pos_emb = d_in[3];
    const void* mod_emb = d_in[4];
    const void* Wv = d_in[5];
    const void* bv = d_in[6];
    const void* nv_g = d_in[7];
    const void* nv_b = d_in[8];
    const void* emb_g = d_in[9];
    const void* emb_b = d_in[10];
    const void* Wq = d_in[11];
    const void* bq = d_in[12];
    const void* Wk = d_in[13];
    const void* bk = d_in[14];
    const void* Wva = d_in[15];
    const void* bva = d_in[16];
    const void* Wo = d_in[17];
    const void* bo = d_in[18];
    const void* ln1_g = d_in[19];
    const void* ln1_b = d_in[20];
    const void* W1 = d_in[21];
    const void* b1 = d_in[22];
    const void* W2 = d_in[23];
    const void* b2 = d_in[24];
    const void* ln2_g = d_in[25];
    const void* ln2_b = d_in[26];

    char* wsb = (char*)d_ws;
    size_t off = 0;
    auto alloc = [&](size_t bytes) -> void* {
        void* p = (void*)(wsb + off);
        off += (bytes + 4095) & ~((size_t)4095);
        return p;
    };
    int* flag = (int*)alloc(16);
    u16* WvT = (u16*)alloc((size_t)Dd * FDd * 2);
    u16 *WqkvT[NL], *WoT[NL], *W1T[NL], *W2T[NL];
    for (int i = 0; i < NL; i++) {
        WqkvT[i] = (u16*)alloc((size_t)3 * Dd * Dd * 2);
        WoT[i] = (u16*)alloc((size_t)Dd * Dd * 2);
        W1T[i] = (u16*)alloc((size_t)FFf * Dd * 2);
        W2T[i] = (u16*)alloc((size_t)Dd * FFf * 2);
    }
    u16* x = (u16*)alloc((size_t)Bb * Ss * Dd * 2);    // 32 MB residual stream (bf16)
    u16* tmp = (u16*)alloc((size_t)Bb * Ss * Dd * 2);  // 32 MB bf16 GEMM out
    char* uni = (char*)alloc((size_t)134217728);       // union region (lifetimes disjoint)
    u16* videob = (u16*)uni;                           // video bf16   [dead after video GEMM]
    u16* qb = (u16*)uni;                               // q            [B,H,S,DH]
    u16* kb = (u16*)(uni + 33554432);                  // k            [B,H,S,DH]
    u16* vtb = (u16*)(uni + 67108864);                 // v^T          [B,H,DH,S]
    u16* ctxb = (u16*)(uni + 100663296);               // ctx          [B,S,D]
    u16* hb = (u16*)uni;                               // FFN hidden   [B,S,FF] (128 MB)

    dim3 tb(32, 8);

    probe_kernel<<<dim3(1), dim3(64), 0, stream>>>(pos_emb, flag);
    convert_kernel<<<dim3(8192), dim3(256), 0, stream>>>(video, videob, (long)Bb * Tt * FDd, flag);

    transpose_kernel<<<dim3(Dd / 32, FDd / 32), tb, 0, stream>>>(Wv, WvT, FDd, Dd, 0L, flag);
    for (int i = 0; i < NL; i++) {
        transpose_kernel<<<dim3(Dd / 32, Dd / 32), tb, 0, stream>>>(Wq, WqkvT[i], Dd, Dd, (long)i * Dd * Dd, flag);
        transpose_kernel<<<dim3(Dd / 32, Dd / 32), tb, 0, stream>>>(Wk, WqkvT[i] + (size_t)Dd * Dd, Dd, Dd, (long)i * Dd * Dd, flag);
        transpose_kernel<<<dim3(Dd / 32, Dd / 32), tb, 0, stream>>>(Wva, WqkvT[i] + (size_t)2 * Dd * Dd, Dd, Dd, (long)i * Dd * Dd, flag);
        transpose_kernel<<<dim3(Dd / 32, Dd / 32), tb, 0, stream>>>(Wo, WoT[i], Dd, Dd, (long)i * Dd * Dd, flag);
        transpose_kernel<<<dim3(FFf / 32, Dd / 32), tb, 0, stream>>>(W1, W1T[i], Dd, FFf, (long)i * Dd * FFf, flag);
        transpose_kernel<<<dim3(Dd / 32, FFf / 32), tb, 0, stream>>>(W2, W2T[i], FFf, Dd, (long)i * FFf * Dd, flag);
    }

    // video projection: [28672,1024] @ [1024,512] -> tmp bf16
    gemm_kernel<0><<<dim3(Dd / 128, (Bb * Tt) / 128), dim3(256), 0, stream>>>(
        videob, WvT, bv, 0L, tmp, Bb * Tt, Dd, FDd, flag);
    embed_kernel<<<dim3((Bb * Ss) / 4), dim3(256), 0, stream>>>(question, pos_emb, mod_emb, tmp,
                                                                nv_g, nv_b, emb_g, emb_b, x, flag);

    for (int i = 0; i < NL; i++) {
        qkv_kernel<<<dim3(12, 256), dim3(256), 0, stream>>>(x, WqkvT[i], bq, bk, bva,
                                                            (long)i * Dd, qb, kb, vtb, flag);
        flash_kernel<<<dim3(2048), dim3(256), 0, stream>>>(qb, kb, vtb, mask, ctxb);
        gemm_kernel<0><<<dim3(4, 256), dim3(256), 0, stream>>>(ctxb, WoT[i], bo, (long)i * Dd, tmp,
                                                               Bb * Ss, Dd, Dd, flag);
        add_ln_kernel<<<dim3((Bb * Ss) / 4), dim3(256), 0, stream>>>(tmp, x, ln1_g, ln1_b,
                                                                     (long)i * Dd, x, 0, flag);
        gemm_kernel<1><<<dim3(16, 256), dim3(256), 0, stream>>>(x, W1T[i], b1, (long)i * FFf, hb,
                                                                Bb * Ss, FFf, Dd, flag);
        gemm_kernel<0><<<dim3(4, 256), dim3(256), 0, stream>>>(hb, W2T[i], b2, (long)i * Dd, tmp,
                                                               Bb * Ss, Dd, FFf, flag);
        void* dst = (i == NL - 1) ? d_out : (void*)x;
        add_ln_kernel<<<dim3((Bb * Ss) / 4), dim3(256), 0, stream>>>(
            tmp, x, ln2_g, ln2_b, (long)i * Dd, dst, (i == NL - 1) ? 1 : 0, flag);
    }
    (void)in_sizes; (void)n_in; (void)out_size; (void)ws_size;
}

// Round 4
// 1446.739 us; speedup vs baseline: 1.2759x; 1.0888x over previous
//
#include <hip/hip_runtime.h>
#include <hip/hip_bf16.h>
#include <stdint.h>

// Problem constants
#define Bb 64
#define Qq 64
#define Tt 448
#define Dd 512
#define FDd 1024
#define Hh 8
#define NL 2
#define FFf 2048
#define Ss 512
#define DHh 64

typedef unsigned short u16;
typedef __bf16 bf16x8 __attribute__((ext_vector_type(8)));
typedef float f32x4 __attribute__((ext_vector_type(4)));
typedef float fv4 __attribute__((ext_vector_type(4)));
typedef u16 u16x4 __attribute__((ext_vector_type(4)));

__device__ __forceinline__ float bf2f(u16 u) { return __uint_as_float(((uint32_t)u) << 16); }
// native RNE f32->bf16 (gfx950 v_cvt_pk_bf16_f32)
__device__ __forceinline__ u16 f2bfu(float f) {
    __bf16 h = (__bf16)f;
    return __builtin_bit_cast(unsigned short, h);
}
// Dual-mode load: input tensors may be bf16 (flag=1) or fp32 (flag=0)
__device__ __forceinline__ float ldx(const void* p, long i, int isbf) {
    return isbf ? bf2f(((const u16*)p)[i]) : ((const float*)p)[i];
}
// fast gelu: x*sigmoid(2c*x*(1+0.044715x^2)), c=0.79788456 (tanh-form, |err|<1e-3)
__device__ __forceinline__ float geluf(float v) {
    float u = v * (1.0f + 0.044715f * v * v) * -1.5957691216057308f;
    return v / (1.0f + __expf(u));
}
// async global->LDS, 16B per lane; lds ptr must be wave-uniform base (HW adds lane*16)
__device__ __forceinline__ void gload16(const void* g, void* l) {
    __builtin_amdgcn_global_load_lds((const __attribute__((address_space(1))) void*)g,
                                     (__attribute__((address_space(3))) void*)l, 16, 0, 0);
}
#define MFMA16(a, b, c) __builtin_amdgcn_mfma_f32_16x16x32_bf16(a, b, c, 0, 0, 0)

// ---------------- dtype probe ----------------
// pos_emb[0,:2] = (sin0, cos0) = (0,1). bf16-packed word = 0x3F800000; fp32 word = 0.
__global__ void probe_kernel(const void* pos_emb, int* flag) {
    if (threadIdx.x == 0) {
        uint32_t w = *(const uint32_t*)pos_emb;
        *flag = (w == 0x3F800000u) ? 1 : 0;
    }
}

// ---------------- convert (video -> canonical bf16) ----------------
__global__ void convert_kernel(const void* __restrict__ src, u16* __restrict__ dst, long n,
                               const int* __restrict__ flag) {
    const int isbf = *flag;
    long i = (long)blockIdx.x * blockDim.x + threadIdx.x;
    long stride = (long)gridDim.x * blockDim.x;
    for (; i < n; i += stride) {
        dst[i] = isbf ? ((const u16*)src)[i] : f2bfu(((const float*)src)[i]);
    }
}

// ---------------- dual-mode weight transpose: W[R,C] -> Wt[C,R] (bf16 out) -------------
__global__ void transpose_kernel(const void* __restrict__ src, u16* __restrict__ dst,
                                 int R, int C, long elem_off, const int* __restrict__ flag) {
    __shared__ u16 tile[32][33];
    const int isbf = *flag;
    const int c0 = blockIdx.x * 32, r0 = blockIdx.y * 32;
    const int tx = threadIdx.x, ty = threadIdx.y;
#pragma unroll
    for (int i = 0; i < 32; i += 8) {
        long idx = elem_off + (long)(r0 + ty + i) * C + (c0 + tx);
        tile[ty + i][tx] = isbf ? ((const u16*)src)[idx] : f2bfu(((const float*)src)[idx]);
    }
    __syncthreads();
#pragma unroll
    for (int i = 0; i < 32; i += 8) {
        dst[(long)(c0 + ty + i) * R + (r0 + tx)] = tile[tx][ty + i];
    }
}

// ---------------- MFMA GEMM: C[M,N] = A[M,K] @ Bt[N,K]^T + bias -------
// MODE 0: out bf16 [M,N];  MODE 1: out bf16 [M,N] + gelu.
// LDS staging XOR-swizzled on the global side: chunk sg = kq ^ ((r>>1)&3) ->
// fragment ds_read_b128 bank-starts tile all 32 banks twice (2-way = free, m136).
template <int MODE, int KK>
__global__ __launch_bounds__(256) void gemm_kernel(const u16* __restrict__ A,
                                                   const u16* __restrict__ Bt,
                                                   const void* __restrict__ bias, long bias_off,
                                                   void* __restrict__ out, int M, int N,
                                                   const int* __restrict__ flag) {
    __shared__ __align__(16) u16 sA[128 * 32];
    __shared__ __align__(16) u16 sB[128 * 32];
    const int tid = threadIdx.x;
    const int lane = tid & 63, wave = tid >> 6;
    const int wm = wave >> 1, wn = wave & 1;
    const int col16 = lane & 15, quad = lane >> 4;
    const long m0 = (long)blockIdx.y * 128;
    const long n0 = (long)blockIdx.x * 128;

    f32x4 acc[4][4];
#pragma unroll
    for (int i = 0; i < 4; i++)
#pragma unroll
        for (int j = 0; j < 4; j++) acc[i][j] = (f32x4){0.f, 0.f, 0.f, 0.f};

    // staging indices (constant across K-steps)
    const int sr = tid >> 2, skq = tid & 3;
    const int ssg = skq ^ ((sr >> 1) & 3);
    const int sr2 = (tid + 256) >> 2, skq2 = tid & 3;
    const int ssg2 = skq2 ^ ((sr2 >> 1) & 3);

#pragma unroll
    for (int k0 = 0; k0 < KK; k0 += 32) {
        __syncthreads();
        {
            int lbase = (wave * 64) * 8;
            gload16(&A[(m0 + sr) * KK + k0 + ssg * 8], &sA[lbase]);
            gload16(&Bt[(n0 + sr) * KK + k0 + ssg * 8], &sB[lbase]);
            int lbase2 = (256 + wave * 64) * 8;
            gload16(&A[(m0 + sr2) * KK + k0 + ssg2 * 8], &sA[lbase2]);
            gload16(&Bt[(n0 + sr2) * KK + k0 + ssg2 * 8], &sB[lbase2]);
        }
        __syncthreads();
        bf16x8 af[4], bfv[4];
#pragma unroll
        for (int mi = 0; mi < 4; mi++) {
            int rr = wm * 64 + mi * 16 + col16;
            af[mi] = *(const bf16x8*)&sA[(rr * 4 + (quad ^ ((rr >> 1) & 3))) * 8];
        }
#pragma unroll
        for (int ni = 0; ni < 4; ni++) {
            int rr = wn * 64 + ni * 16 + col16;
            bfv[ni] = *(const bf16x8*)&sB[(rr * 4 + (quad ^ ((rr >> 1) & 3))) * 8];
        }
#pragma unroll
        for (int mi = 0; mi < 4; mi++)
#pragma unroll
            for (int ni = 0; ni < 4; ni++)
                acc[mi][ni] = MFMA16(af[mi], bfv[ni], acc[mi][ni]);
    }

    const int isbf = *flag;
    float bb[4];
#pragma unroll
    for (int ni = 0; ni < 4; ni++)
        bb[ni] = ldx(bias, bias_off + n0 + wn * 64 + ni * 16 + col16, isbf);

#pragma unroll
    for (int mi = 0; mi < 4; mi++) {
#pragma unroll
        for (int ni = 0; ni < 4; ni++) {
            long col = n0 + wn * 64 + ni * 16 + col16;
#pragma unroll
            for (int r = 0; r < 4; r++) {
                long row = m0 + wm * 64 + mi * 16 + quad * 4 + r;
                float v = acc[mi][ni][r] + bb[ni];
                if (MODE == 0) {
                    ((u16*)out)[row * N + col] = f2bfu(v);
                } else {
                    ((u16*)out)[row * N + col] = f2bfu(geluf(v));
                }
            }
        }
    }
}

// ---------------- fused QKV GEMM: A[M,512] @ WqkvT[1536,512]^T, scatter epilogue --------
// WqkvT rows 0-511 = Wq^T, 512-1023 = Wk^T, 1024-1535 = Wva^T. 128-col blocks never
// straddle a 512 boundary -> region is block-uniform.
__global__ __launch_bounds__(256) void qkv_kernel(const u16* __restrict__ A,
                                                  const u16* __restrict__ Bt,
                                                  const void* __restrict__ bq,
                                                  const void* __restrict__ bk,
                                                  const void* __restrict__ bva, long boff,
                                                  u16* __restrict__ qb, u16* __restrict__ kb,
                                                  u16* __restrict__ vtb,
                                                  const int* __restrict__ flag) {
    __shared__ __align__(16) u16 sA[128 * 32];
    __shared__ __align__(16) u16 sB[128 * 32];
    const int tid = threadIdx.x;
    const int lane = tid & 63, wave = tid >> 6;
    const int wm = wave >> 1, wn = wave & 1;
    const int col16 = lane & 15, quad = lane >> 4;
    const long m0 = (long)blockIdx.y * 128;
    const long n0 = (long)blockIdx.x * 128;
    const int KK = Dd;

    f32x4 acc[4][4];
#pragma unroll
    for (int i = 0; i < 4; i++)
#pragma unroll
        for (int j = 0; j < 4; j++) acc[i][j] = (f32x4){0.f, 0.f, 0.f, 0.f};

    const int sr = tid >> 2, skq = tid & 3;
    const int ssg = skq ^ ((sr >> 1) & 3);
    const int sr2 = (tid + 256) >> 2;
    const int ssg2 = skq ^ ((sr2 >> 1) & 3);

#pragma unroll
    for (int k0 = 0; k0 < KK; k0 += 32) {
        __syncthreads();
        {
            int lbase = (wave * 64) * 8;
            gload16(&A[(m0 + sr) * KK + k0 + ssg * 8], &sA[lbase]);
            gload16(&Bt[(n0 + sr) * KK + k0 + ssg * 8], &sB[lbase]);
            int lbase2 = (256 + wave * 64) * 8;
            gload16(&A[(m0 + sr2) * KK + k0 + ssg2 * 8], &sA[lbase2]);
            gload16(&Bt[(n0 + sr2) * KK + k0 + ssg2 * 8], &sB[lbase2]);
        }
        __syncthreads();
        bf16x8 af[4], bfv[4];
#pragma unroll
        for (int mi = 0; mi < 4; mi++) {
            int rr = wm * 64 + mi * 16 + col16;
            af[mi] = *(const bf16x8*)&sA[(rr * 4 + (quad ^ ((rr >> 1) & 3))) * 8];
        }
#pragma unroll
        for (int ni = 0; ni < 4; ni++) {
            int rr = wn * 64 + ni * 16 + col16;
            bfv[ni] = *(const bf16x8*)&sB[(rr * 4 + (quad ^ ((rr >> 1) & 3))) * 8];
        }
#pragma unroll
        for (int mi = 0; mi < 4; mi++)
#pragma unroll
            for (int ni = 0; ni < 4; ni++)
                acc[mi][ni] = MFMA16(af[mi], bfv[ni], acc[mi][ni]);
    }

    const int isbf = *flag;
    const int region = (int)(n0 >> 9);  // 0=q, 1=k, 2=v (block-uniform)
    const void* bias = (region == 0) ? bq : (region == 1) ? bk : bva;
    float bb[4];
#pragma unroll
    for (int ni = 0; ni < 4; ni++) {
        long col = n0 + wn * 64 + ni * 16 + col16;
        bb[ni] = ldx(bias, boff + (col & 511), isbf);
    }

#pragma unroll
    for (int mi = 0; mi < 4; mi++) {
#pragma unroll
        for (int ni = 0; ni < 4; ni++) {
            long col = n0 + wn * 64 + ni * 16 + col16;
            long cc = col & 511;
            long h = cc >> 6, dh = cc & 63;
            long row0 = m0 + wm * 64 + mi * 16 + quad * 4;
            long b = row0 >> 9, s0 = row0 & 511;
            if (region == 0) {
#pragma unroll
                for (int r = 0; r < 4; r++)
                    qb[(((b * 8 + h) * 512) + s0 + r) * 64 + dh] =
                        f2bfu((acc[mi][ni][r] + bb[ni]) * 0.125f);
            } else if (region == 1) {
#pragma unroll
                for (int r = 0; r < 4; r++)
                    kb[(((b * 8 + h) * 512) + s0 + r) * 64 + dh] = f2bfu(acc[mi][ni][r] + bb[ni]);
            } else {  // v^T: 4 consecutive s for fixed dh -> one 8B store
                u16x4 pk;
#pragma unroll
                for (int r = 0; r < 4; r++) pk[r] = f2bfu(acc[mi][ni][r] + bb[ni]);
                *(u16x4*)&vtb[(((b * 8 + h) * 64) + dh) * 512 + s0] = pk;
            }
        }
    }
}

// ---------------- wave-level LN helpers (one wave per row of 512) ----------------
__device__ __forceinline__ float wredsum(float v) {
#pragma unroll
    for (int off = 1; off < 64; off <<= 1) v += __shfl_xor(v, off);
    return v;
}
__device__ __forceinline__ void ln8(float v[8]) {
    float s = 0.f;
#pragma unroll
    for (int j = 0; j < 8; j++) s += v[j];
    s = wredsum(s);
    float m = s * (1.0f / 512.0f);
    float q = 0.f;
#pragma unroll
    for (int j = 0; j < 8; j++) {
        v[j] -= m;
        q += v[j] * v[j];
    }
    q = wredsum(q);
    float inv = rsqrtf(q * (1.0f / 512.0f) + 1e-12f);
#pragma unroll
    for (int j = 0; j < 8; j++) v[j] *= inv;
}

// ---------------- embed: concat(question, LN(videoproj)) + pos + mod, LN ---------------
__global__ __launch_bounds__(256) void embed_kernel(
    const void* __restrict__ question, const void* __restrict__ pos, const void* __restrict__ mod,
    const u16* __restrict__ tmp, const void* __restrict__ nvg, const void* __restrict__ nvb,
    const void* __restrict__ eg, const void* __restrict__ eb, u16* __restrict__ x,
    const int* __restrict__ flag) {
    const int isbf = *flag;
    const int wave = threadIdx.x >> 6, lane = threadIdx.x & 63;
    const long row = (long)blockIdx.x * 4 + wave;
    const int b = (int)(row >> 9), s = (int)(row & 511);
    const int d0 = lane * 4, d1 = 256 + lane * 4;
    float v[8];
    if (s < Qq) {
        long base = ((long)b * Qq + s) * Dd;
#pragma unroll
        for (int j = 0; j < 4; j++) {
            v[j] = ldx(question, base + d0 + j, isbf);
            v[4 + j] = ldx(question, base + d1 + j, isbf);
        }
    } else {
        const u16* tr = tmp + ((long)b * Tt + (s - Qq)) * Dd;
        u16x4 f0 = *(const u16x4*)(tr + d0);
        u16x4 f1 = *(const u16x4*)(tr + d1);
#pragma unroll
        for (int j = 0; j < 4; j++) {
            v[j] = bf2f(f0[j]);
            v[4 + j] = bf2f(f1[j]);
        }
        ln8(v);
#pragma unroll
        for (int j = 0; j < 4; j++) {
            v[j] = v[j] * ldx(nvg, d0 + j, isbf) + ldx(nvb, d0 + j, isbf);
            v[4 + j] = v[4 + j] * ldx(nvg, d1 + j, isbf) + ldx(nvb, d1 + j, isbf);
        }
    }
    const int mid = (s < Qq) ? 0 : 1;
#pragma unroll
    for (int j = 0; j < 4; j++) {
        v[j] += ldx(pos, (long)s * Dd + d0 + j, isbf) + ldx(mod, (long)mid * Dd + d0 + j, isbf);
        v[4 + j] += ldx(pos, (long)s * Dd + d1 + j, isbf) + ldx(mod, (long)mid * Dd + d1 + j, isbf);
    }
    ln8(v);
#pragma unroll
    for (int j = 0; j < 4; j++) {
        x[row * Dd + d0 + j] = f2bfu(v[j] * ldx(eg, d0 + j, isbf) + ldx(eb, d0 + j, isbf));
        x[row * Dd + d1 + j] = f2bfu(v[4 + j] * ldx(eg, d1 + j, isbf) + ldx(eb, d1 + j, isbf));
    }
}

// ---------------- add residual + LN (tmp is bf16) ----------------
__global__ __launch_bounds__(256) void add_ln_kernel(const u16* __restrict__ tmp,
                                                     const u16* __restrict__ xin,
                                                     const void* __restrict__ g,
                                                     const void* __restrict__ bta, long goff,
                                                     void* __restrict__ dst, int dst_is_final,
                                                     const int* __restrict__ flag) {
    const int isbf = *flag;
    const int wave = threadIdx.x >> 6, lane = threadIdx.x & 63;
    const long row = (long)blockIdx.x * 4 + wave;
    const int d0 = lane * 4, d1 = 256 + lane * 4;
    u16x4 t0 = *(const u16x4*)(tmp + row * Dd + d0);
    u16x4 t1 = *(const u16x4*)(tmp + row * Dd + d1);
    u16x4 x0 = *(const u16x4*)(xin + row * Dd + d0);
    u16x4 x1 = *(const u16x4*)(xin + row * Dd + d1);
    float v[8];
#pragma unroll
    for (int j = 0; j < 4; j++) {
        v[j] = bf2f(t0[j]) + bf2f(x0[j]);
        v[4 + j] = bf2f(t1[j]) + bf2f(x1[j]);
    }
    ln8(v);
#pragma unroll
    for (int j = 0; j < 8; j++) {
        int d = (j < 4) ? d0 + j : d1 + j - 4;
        v[j] = v[j] * ldx(g, goff + d, isbf) + ldx(bta, goff + d, isbf);
    }
    if (dst_is_final && !isbf) {
#pragma unroll
        for (int j = 0; j < 4; j++) {
            ((float*)dst)[row * Dd + d0 + j] = v[j];
            ((float*)dst)[row * Dd + d1 + j] = v[4 + j];
        }
    } else {
#pragma unroll
        for (int j = 0; j < 4; j++) {
            ((u16*)dst)[row * Dd + d0 + j] = f2bfu(v[j]);
            ((u16*)dst)[row * Dd + d1 + j] = f2bfu(v[4 + j]);
        }
    }
}

// ---------------- flash attention v3: LDS-staged K/V, MFMA row-sums, native bf16 cvt ----
// q,k: [B,H,S,DH] bf16 (q pre-scaled); vT: [B,H,DH,S] bf16; ctx out: [B,S,D] bf16
// grid: 1D, bid = qt*512 + bh -> blocks sharing (b,h) on same XCD (bid%8 const).
// Online softmax with deferred normalization: l accumulated as P@1 via an extra MFMA.
__global__ __launch_bounds__(256) void flash_kernel(const u16* __restrict__ q,
                                                    const u16* __restrict__ k,
                                                    const u16* __restrict__ vT,
                                                    const int* __restrict__ mask,
                                                    u16* __restrict__ ctx) {
    __shared__ __align__(16) u16 sK[64 * 64];
    __shared__ __align__(16) u16 sV[64 * 64];
    __shared__ __align__(16) u16 pbuf[4][16 * 72];
    __shared__ float smaskf[Ss];

    const int tid = threadIdx.x;
    const int lane = tid & 63, wave = tid >> 6;
    const int col16 = lane & 15, quad = lane >> 4;
    const int bid = blockIdx.x;
    const int qt = bid >> 9;
    const int bh = bid & 511;
    const int b = bh & 63, h = bh >> 6;
    const long bhl = (long)b * Hh + h;
    const u16* qp = q + bhl * Ss * DHh;
    const u16* kp = k + bhl * Ss * DHh;
    const u16* vp = vT + bhl * DHh * Ss;

    smaskf[tid] = mask[b * Ss + tid] ? 0.f : -1e30f;
    smaskf[tid + 256] = mask[b * Ss + tid + 256] ? 0.f : -1e30f;

    const int qbase = qt * 128 + wave * 32;
    bf16x8 aq[2][2];
#pragma unroll
    for (int t = 0; t < 2; t++) {
        aq[t][0] = *(const bf16x8*)&qp[(qbase + t * 16 + col16) * 64 + quad * 8];
        aq[t][1] = *(const bf16x8*)&qp[(qbase + t * 16 + col16) * 64 + 32 + quad * 8];
    }

    bf16x8 vone;
#pragma unroll
    for (int j = 0; j < 8; j++) vone[j] = (__bf16)1.0f;

    float mr[2][4];
    f32x4 acc[2][4], accl[2];
#pragma unroll
    for (int t = 0; t < 2; t++) {
        accl[t] = (f32x4){0.f, 0.f, 0.f, 0.f};
#pragma unroll
        for (int r = 0; r < 4; r++) mr[t][r] = -1e30f;
#pragma unroll
        for (int dt = 0; dt < 4; dt++) acc[t][dt] = (f32x4){0.f, 0.f, 0.f, 0.f};
    }

    for (int c0 = 0; c0 < Ss; c0 += 64) {
        __syncthreads();
#pragma unroll
        for (int i = 0; i < 2; i++) {
            int ci = i * 256 + tid;
            int row = ci >> 3, sl = ci & 7;
            int sg = sl ^ (row & 7);  // xor swizzle on the GLOBAL side
            int lbase = (i * 256 + wave * 64) * 8;
            gload16(&kp[(c0 + row) * 64 + sg * 8], &sK[lbase]);
            gload16(&vp[row * 512 + c0 + sg * 8], &sV[lbase]);
        }
        __syncthreads();

        bf16x8 bk[4][2];
#pragma unroll
        for (int nt = 0; nt < 4; nt++) {
            int r = nt * 16 + col16;
            bk[nt][0] = *(const bf16x8*)&sK[(r * 8 + (quad ^ (r & 7))) * 8];
            bk[nt][1] = *(const bf16x8*)&sK[(r * 8 + ((4 + quad) ^ (r & 7))) * 8];
        }

#pragma unroll
        for (int t = 0; t < 2; t++) {
            f32x4 sc[4];
#pragma unroll
            for (int nt = 0; nt < 4; nt++) {
                f32x4 z = (f32x4){0.f, 0.f, 0.f, 0.f};
                z = MFMA16(aq[t][0], bk[nt][0], z);
                z = MFMA16(aq[t][1], bk[nt][1], z);
                float mf = smaskf[c0 + nt * 16 + col16];
#pragma unroll
                for (int r = 0; r < 4; r++) z[r] += mf;
                sc[nt] = z;
            }
            float alpha[4];
#pragma unroll
            for (int r = 0; r < 4; r++) {
                float cm = fmaxf(fmaxf(sc[0][r], sc[1][r]), fmaxf(sc[2][r], sc[3][r]));
#pragma unroll
                for (int off = 1; off < 16; off <<= 1) cm = fmaxf(cm, __shfl_xor(cm, off));
                float mn = fmaxf(mr[t][r], cm);
                alpha[r] = __expf(mr[t][r] - mn);  // mr<=mn always; ==0 on first chunk
                mr[t][r] = mn;
#pragma unroll
                for (int nt = 0; nt < 4; nt++)
                    pbuf[wave][(quad * 4 + r) * 72 + nt * 16 + col16] =
                        f2bfu(__expf(sc[nt][r] - mn));
            }
#pragma unroll
            for (int dt = 0; dt < 4; dt++) {
#pragma unroll
                for (int r = 0; r < 4; r++) acc[t][dt][r] *= alpha[r];
            }
#pragma unroll
            for (int r = 0; r < 4; r++) accl[t][r] *= alpha[r];
            // P (C-layout) -> A-operand layout via per-wave LDS (same-wave DS is in-order)
#pragma unroll
            for (int hf = 0; hf < 2; hf++) {
                bf16x8 ap = *(const bf16x8*)&pbuf[wave][col16 * 72 + hf * 32 + quad * 8];
#pragma unroll
                for (int dt = 0; dt < 4; dt++) {
                    int d = dt * 16 + col16;
                    bf16x8 bv = *(const bf16x8*)&sV[(d * 8 + ((hf * 4 + quad) ^ (d & 7))) * 8];
                    acc[t][dt] = MFMA16(ap, bv, acc[t][dt]);
                }
                accl[t] = MFMA16(ap, vone, accl[t]);  // row-sum column (deferred l)
            }
        }
    }
#pragma unroll
    for (int t = 0; t < 2; t++)
#pragma unroll
        for (int dt = 0; dt < 4; dt++) {
#pragma unroll
            for (int r = 0; r < 4; r++) {
                float v = acc[t][dt][r] / accl[t][r];
                int sq = qbase + t * 16 + quad * 4 + r;
                int d = h * 64 + dt * 16 + col16;
                ctx[((long)b * Ss + sq) * Dd + d] = f2bfu(v);
            }
        }
}

// ---------------- host ----------------
extern "C" void kernel_launch(void* const* d_in, const int* in_sizes, int n_in, void* d_out,
                              int out_size, void* d_ws, size_t ws_size, hipStream_t stream) {
    const void* video = d_in[0];
    const void* question = d_in[1];
    const int* mask = (const int*)d_in[2];
    const void* pos_emb = d_in[3];
    const void* mod_emb = d_in[4];
    const void* Wv = d_in[5];
    const void* bv = d_in[6];
    const void* nv_g = d_in[7];
    const void* nv_b = d_in[8];
    const void* emb_g = d_in[9];
    const void* emb_b = d_in[10];
    const void* Wq = d_in[11];
    const void* bq = d_in[12];
    const void* Wk = d_in[13];
    const void* bk = d_in[14];
    const void* Wva = d_in[15];
    const void* bva = d_in[16];
    const void* Wo = d_in[17];
    const void* bo = d_in[18];
    const void* ln1_g = d_in[19];
    const void* ln1_b = d_in[20];
    const void* W1 = d_in[21];
    const void* b1 = d_in[22];
    const void* W2 = d_in[23];
    const void* b2 = d_in[24];
    const void* ln2_g = d_in[25];
    const void* ln2_b = d_in[26];

    char* wsb = (char*)d_ws;
    size_t off = 0;
    auto alloc = [&](size_t bytes) -> void* {
        void* p = (void*)(wsb + off);
        off += (bytes + 4095) & ~((size_t)4095);
        return p;
    };
    int* flag = (int*)alloc(16);
    u16* WvT = (u16*)alloc((size_t)Dd * FDd * 2);
    u16 *WqkvT[NL], *WoT[NL], *W1T[NL], *W2T[NL];
    for (int i = 0; i < NL; i++) {
        WqkvT[i] = (u16*)alloc((size_t)3 * Dd * Dd * 2);
        WoT[i] = (u16*)alloc((size_t)Dd * Dd * 2);
        W1T[i] = (u16*)alloc((size_t)FFf * Dd * 2);
        W2T[i] = (u16*)alloc((size_t)Dd * FFf * 2);
    }
    u16* x = (u16*)alloc((size_t)Bb * Ss * Dd * 2);    // 32 MB residual stream (bf16)
    u16* tmp = (u16*)alloc((size_t)Bb * Ss * Dd * 2);  // 32 MB bf16 GEMM out
    char* uni = (char*)alloc((size_t)134217728);       // union region (lifetimes disjoint)
    u16* videob = (u16*)uni;                           // video bf16   [dead after video GEMM]
    u16* qb = (u16*)uni;                               // q            [B,H,S,DH]
    u16* kb = (u16*)(uni + 33554432);                  // k            [B,H,S,DH]
    u16* vtb = (u16*)(uni + 67108864);                 // v^T          [B,H,DH,S]
    u16* ctxb = (u16*)(uni + 100663296);               // ctx          [B,S,D]
    u16* hb = (u16*)uni;                               // FFN hidden   [B,S,FF] (128 MB)

    dim3 tb(32, 8);

    probe_kernel<<<dim3(1), dim3(64), 0, stream>>>(pos_emb, flag);
    convert_kernel<<<dim3(8192), dim3(256), 0, stream>>>(video, videob, (long)Bb * Tt * FDd, flag);

    transpose_kernel<<<dim3(Dd / 32, FDd / 32), tb, 0, stream>>>(Wv, WvT, FDd, Dd, 0L, flag);
    for (int i = 0; i < NL; i++) {
        transpose_kernel<<<dim3(Dd / 32, Dd / 32), tb, 0, stream>>>(Wq, WqkvT[i], Dd, Dd, (long)i * Dd * Dd, flag);
        transpose_kernel<<<dim3(Dd / 32, Dd / 32), tb, 0, stream>>>(Wk, WqkvT[i] + (size_t)Dd * Dd, Dd, Dd, (long)i * Dd * Dd, flag);
        transpose_kernel<<<dim3(Dd / 32, Dd / 32), tb, 0, stream>>>(Wva, WqkvT[i] + (size_t)2 * Dd * Dd, Dd, Dd, (long)i * Dd * Dd, flag);
        transpose_kernel<<<dim3(Dd / 32, Dd / 32), tb, 0, stream>>>(Wo, WoT[i], Dd, Dd, (long)i * Dd * Dd, flag);
        transpose_kernel<<<dim3(FFf / 32, Dd / 32), tb, 0, stream>>>(W1, W1T[i], Dd, FFf, (long)i * Dd * FFf, flag);
        transpose_kernel<<<dim3(Dd / 32, FFf / 32), tb, 0, stream>>>(W2, W2T[i], FFf, Dd, (long)i * FFf * Dd, flag);
    }

    // video projection: [28672,1024] @ [1024,512] -> tmp bf16
    gemm_kernel<0, FDd><<<dim3(Dd / 128, (Bb * Tt) / 128), dim3(256), 0, stream>>>(
        videob, WvT, bv, 0L, tmp, Bb * Tt, Dd, flag);
    embed_kernel<<<dim3((Bb * Ss) / 4), dim3(256), 0, stream>>>(question, pos_emb, mod_emb, tmp,
                                                                nv_g, nv_b, emb_g, emb_b, x, flag);

    for (int i = 0; i < NL; i++) {
        qkv_kernel<<<dim3(12, 256), dim3(256), 0, stream>>>(x, WqkvT[i], bq, bk, bva,
                                                            (long)i * Dd, qb, kb, vtb, flag);
        flash_kernel<<<dim3(2048), dim3(256), 0, stream>>>(qb, kb, vtb, mask, ctxb);
        gemm_kernel<0, Dd><<<dim3(4, 256), dim3(256), 0, stream>>>(ctxb, WoT[i], bo, (long)i * Dd,
                                                                   tmp, Bb * Ss, Dd, flag);
        add_ln_kernel<<<dim3((Bb * Ss) / 4), dim3(256), 0, stream>>>(tmp, x, ln1_g, ln1_b,
                                                                     (long)i * Dd, x, 0, flag);
        gemm_kernel<1, Dd><<<dim3(16, 256), dim3(256), 0, stream>>>(x, W1T[i], b1, (long)i * FFf,
                                                                    hb, Bb * Ss, FFf, flag);
        gemm_kernel<0, FFf><<<dim3(4, 256), dim3(256), 0, stream>>>(hb, W2T[i], b2, (long)i * Dd,
                                                                    tmp, Bb * Ss, Dd, flag);
        void* dst = (i == NL - 1) ? d_out : (void*)x;
        add_ln_kernel<<<dim3((Bb * Ss) / 4), dim3(256), 0, stream>>>(
            tmp, x, ln2_g, ln2_b, (long)i * Dd, dst, (i == NL - 1) ? 1 : 0, flag);
    }
    (void)in_sizes; (void)n_in; (void)out_size; (void)ws_size;
}